// Round 8
// baseline (575.334 us; speedup 1.0000x reference)
//
#include <hip/hip_runtime.h>

// ---------------------------------------------------------------------------
// LearnableCurvGCN, round 7: de-contend the counting sort, fatten the gather.
//
// R6 counters: k_reorder 131us @ VALUBusy 2.9% / HBM 16% — wcnt atomic
// serialization (~16 hits/node) + 151MB write amplification (8B+4B random
// stores -> full sectors). Changes:
//   - NREP=8 replicated histogram AND replicated cursors: wcnt8[r][n] is
//     pre-seeded to rp[n] + sum_{r'<r} cnt4[r'][n] (k_init_cursor), so the
//     reorder's atomicAdd returns the absolute position. Contention /8,
//     deterministic bucket layout per replica.
//   - nd[] (node-of-position) deleted: norm pass is CSR-style per node.
//   - gather: float4 per thread (32 threads/node @ DIM=128), 8-deep unroll
//     -> 128B of independent gather traffic in flight per thread.
//
// Pipeline:
//   1. k_edge_cnt    : cnt4[b&7][dst]++
//   2. k_scan_*      : rp = exclusive_scan(sum_r cnt4)
//   3. k_init_cursor : wcnt8[r][n] = rp[n] + prefix_r(cnt4[.][n])
//   4. k_reorder     : MLP(curv)->ew; pos=atomicAdd(wcnt8[b&7][dst]);
//                      ep[pos]=(src,ew)
//   5. k_deg_dis     : dis[n] = rsqrt(bucket_sum(ew)+1)
//   6. k_norm        : per node: ep[i].y = dis[src]*ew*dis[n]
//   7. k_gemm        : xw1 = x @ W1
//   8. k_gather      : h1 = relu(csr_gather + dis^2*xw1 + b1)
//   9. k_gemm        : xw2 = h1 @ W2
//  10. k_gather      : out = csr_gather + dis^2*xw2 + b2
// ---------------------------------------------------------------------------

constexpr int N_NODES = 100000;
constexpr int N_EDGES = 1600000;
constexpr int IN_DIM  = 128;
constexpr int HID_DIM = 128;
constexpr int OUT_DIM = 64;
constexpr int NREP    = 8;     // histogram/cursor replicas

constexpr int SCAN_CHUNK = 512;
constexpr int SCAN_NB    = (N_NODES + SCAN_CHUNK - 1) / SCAN_CHUNK; // 196

// --- tiny curvature MLP (16-wide) -------------------------------------------
__device__ __forceinline__ float edge_weight_mlp(float c,
                                                 const float* __restrict__ mw1,
                                                 const float* __restrict__ mb1,
                                                 const float* __restrict__ mw2,
                                                 const float* __restrict__ mb2)
{
    float z = mb2[0];
#pragma unroll
    for (int i = 0; i < 16; ++i) {
        float h = fmaf(c, mw1[i], mb1[i]);
        h = fmaxf(h, 0.0f);
        z = fmaf(h, mw2[i], z);
    }
    float s = 1.0f / (1.0f + __expf(-z));
    return fmaf(0.9f, s, 0.1f);
}

// --- 1. replicated in-degree histogram ---------------------------------------
__global__ void k_edge_cnt(const int* __restrict__ dst,
                           int* __restrict__ cnt4)
{
    int e = blockIdx.x * blockDim.x + threadIdx.x;
    if (e >= N_EDGES) return;
    atomicAdd(&cnt4[(blockIdx.x & (NREP - 1)) * N_NODES + dst[e]], 1);
}

// --- 2a. per-chunk reduce over replica-summed counts --------------------------
__global__ __launch_bounds__(256) void k_scan_part(const int* __restrict__ cnt4,
                                                   int* __restrict__ bsum)
{
    const int b = blockIdx.x;
    const int t = threadIdx.x;
    const int i = b * SCAN_CHUNK + 2 * t;
    int s = 0;
#pragma unroll
    for (int r = 0; r < NREP; ++r) {
        if (i < N_NODES)     s += cnt4[r * N_NODES + i];
        if (i + 1 < N_NODES) s += cnt4[r * N_NODES + i + 1];
    }
#pragma unroll
    for (int o = 32; o > 0; o >>= 1) s += __shfl_down(s, o, 64);
    __shared__ int ws[4];
    if ((t & 63) == 0) ws[t >> 6] = s;
    __syncthreads();
    if (t == 0) bsum[b] = ws[0] + ws[1] + ws[2] + ws[3];
}

// --- 2b. scan the 196 partials; rp[N] = total ---------------------------------
__global__ __launch_bounds__(256) void k_scan_mid(int* __restrict__ bsum,
                                                  int* __restrict__ rp)
{
    const int t = threadIdx.x;
    int v = (t < SCAN_NB) ? bsum[t] : 0;
    __shared__ int sm[256];
    sm[t] = v;
    __syncthreads();
#pragma unroll
    for (int o = 1; o < 256; o <<= 1) {
        int u = (t >= o) ? sm[t - o] : 0;
        __syncthreads();
        sm[t] += u;
        __syncthreads();
    }
    if (t < SCAN_NB) bsum[t] = sm[t] - v;
    if (t == SCAN_NB - 1) rp[N_NODES] = sm[t];
}

// --- 2c. in-chunk exclusive scan + chunk offset -> rp -------------------------
__global__ __launch_bounds__(256) void k_scan_final(const int* __restrict__ cnt4,
                                                    int* __restrict__ rp,
                                                    const int* __restrict__ bsum)
{
    const int b = blockIdx.x;
    const int t = threadIdx.x;
    const int i = b * SCAN_CHUNK + 2 * t;
    int c0 = 0, c1 = 0;
#pragma unroll
    for (int r = 0; r < NREP; ++r) {
        if (i < N_NODES)     c0 += cnt4[r * N_NODES + i];
        if (i + 1 < N_NODES) c1 += cnt4[r * N_NODES + i + 1];
    }
    int s = c0 + c1;
    __shared__ int sm[256];
    sm[t] = s;
    __syncthreads();
#pragma unroll
    for (int o = 1; o < 256; o <<= 1) {
        int u = (t >= o) ? sm[t - o] : 0;
        __syncthreads();
        sm[t] += u;
        __syncthreads();
    }
    int excl = sm[t] - s + bsum[b];
    if (i < N_NODES)     rp[i]     = excl;
    if (i + 1 < N_NODES) rp[i + 1] = excl + c0;
}

// --- 3. seed replica cursors: wcnt8[r][n] = rp[n] + prefix_r(cnt4[.][n]) ------
__global__ void k_init_cursor(const int* __restrict__ cnt4,
                              const int* __restrict__ rp,
                              int* __restrict__ wcnt8)
{
    int n = blockIdx.x * blockDim.x + threadIdx.x;
    if (n >= N_NODES) return;
    int run = rp[n];
#pragma unroll
    for (int r = 0; r < NREP; ++r) {
        wcnt8[r * N_NODES + n] = run;
        run += cnt4[r * N_NODES + n];
    }
}

// --- 4. bucket edges by dst: ep=(src, ew) -------------------------------------
__global__ void k_reorder(const float* __restrict__ curv,
                          const int*   __restrict__ src,
                          const int*   __restrict__ dst,
                          const float* __restrict__ mw1,
                          const float* __restrict__ mb1,
                          const float* __restrict__ mw2,
                          const float* __restrict__ mb2,
                          int*   __restrict__ wcnt8,
                          int2*  __restrict__ ep)
{
    int e = blockIdx.x * blockDim.x + threadIdx.x;
    if (e >= N_EDGES) return;
    float w = edge_weight_mlp(curv[e], mw1, mb1, mw2, mb2);
    int t = dst[e];
    int pos = atomicAdd(&wcnt8[(blockIdx.x & (NREP - 1)) * N_NODES + t], 1);
    ep[pos] = make_int2(src[e], __float_as_int(w));
}

// --- 5. dis[n] = rsqrt(bucket_sum(ew) + 1) ------------------------------------
__global__ void k_deg_dis(const int*  __restrict__ rp,
                          const int2* __restrict__ ep,
                          float* __restrict__ dis)
{
    int n = blockIdx.x * blockDim.x + threadIdx.x;
    if (n >= N_NODES) return;
    int beg = rp[n], end = rp[n + 1];
    float s = 0.0f;
    for (int i = beg; i < end; ++i)
        s += __int_as_float(ep[i].y);
    dis[n] = rsqrtf(s + 1.0f);
}

// --- 6. norm pass (CSR-style): ep[i].y = dis[src]*ew*dis[n] -------------------
__global__ void k_norm(const int* __restrict__ rp,
                       const float* __restrict__ dis,
                       int2* __restrict__ ep)
{
    int n = blockIdx.x * blockDim.x + threadIdx.x;
    if (n >= N_NODES) return;
    float dn = dis[n];
    int beg = rp[n], end = rp[n + 1];
    for (int i = beg; i < end; ++i) {
        int2 e = ep[i];
        ep[i] = make_int2(e.x, __float_as_int(dis[e.x] * __int_as_float(e.y) * dn));
    }
}

// --- 7/9. fp32 GEMM: C[N,KOUT] = A[N,KIN] @ W[KIN,KOUT] -----------------------
template <int KIN, int KOUT>
__global__ __launch_bounds__(256) void k_gemm(const float* __restrict__ A,
                                              const float* __restrict__ W,
                                              float* __restrict__ C)
{
    constexpr int CQ  = KOUT / 4;
    constexpr int RPB = 4 * (256 / CQ);
    const int tid = threadIdx.x;
    const int cq  = tid % CQ;
    const int rg  = tid / CQ;
    const int r0  = blockIdx.x * RPB + 4 * rg;
    if (r0 >= N_NODES) return;               // 4-row granularity, N%4==0
    const float* a0 = A + (size_t)r0 * KIN;
    const float* a1 = a0 + KIN;
    const float* a2 = a1 + KIN;
    const float* a3 = a2 + KIN;
    float4 acc0 = {0,0,0,0}, acc1 = {0,0,0,0}, acc2 = {0,0,0,0}, acc3 = {0,0,0,0};
#pragma unroll 4
    for (int k = 0; k < KIN; k += 4) {
        float4 x0 = *reinterpret_cast<const float4*>(&a0[k]);
        float4 x1 = *reinterpret_cast<const float4*>(&a1[k]);
        float4 x2 = *reinterpret_cast<const float4*>(&a2[k]);
        float4 x3 = *reinterpret_cast<const float4*>(&a3[k]);
        const float* xs0 = &x0.x;
        const float* xs1 = &x1.x;
        const float* xs2 = &x2.x;
        const float* xs3 = &x3.x;
#pragma unroll
        for (int kk = 0; kk < 4; ++kk) {
            float4 w = *reinterpret_cast<const float4*>(&W[(k + kk) * KOUT + 4 * cq]);
            float f0 = xs0[kk], f1 = xs1[kk], f2 = xs2[kk], f3 = xs3[kk];
            acc0.x = fmaf(f0, w.x, acc0.x); acc0.y = fmaf(f0, w.y, acc0.y);
            acc0.z = fmaf(f0, w.z, acc0.z); acc0.w = fmaf(f0, w.w, acc0.w);
            acc1.x = fmaf(f1, w.x, acc1.x); acc1.y = fmaf(f1, w.y, acc1.y);
            acc1.z = fmaf(f1, w.z, acc1.z); acc1.w = fmaf(f1, w.w, acc1.w);
            acc2.x = fmaf(f2, w.x, acc2.x); acc2.y = fmaf(f2, w.y, acc2.y);
            acc2.z = fmaf(f2, w.z, acc2.z); acc2.w = fmaf(f2, w.w, acc2.w);
            acc3.x = fmaf(f3, w.x, acc3.x); acc3.y = fmaf(f3, w.y, acc3.y);
            acc3.z = fmaf(f3, w.z, acc3.z); acc3.w = fmaf(f3, w.w, acc3.w);
        }
    }
    *reinterpret_cast<float4*>(&C[(size_t)r0 * KOUT + 4 * cq])       = acc0;
    *reinterpret_cast<float4*>(&C[(size_t)(r0 + 1) * KOUT + 4 * cq]) = acc1;
    *reinterpret_cast<float4*>(&C[(size_t)(r0 + 2) * KOUT + 4 * cq]) = acc2;
    *reinterpret_cast<float4*>(&C[(size_t)(r0 + 3) * KOUT + 4 * cq]) = acc3;
}

// --- 8/10. CSR gather, float4/thread, 8-deep unroll, fused finalize -----------
template <int DIM, bool RELU>
__global__ __launch_bounds__(256) void k_gather(const int*  __restrict__ rp,
                                                const int2* __restrict__ ep,
                                                const float* __restrict__ xw,
                                                const float* __restrict__ dis,
                                                const float* __restrict__ bias,
                                                float* __restrict__ out)
{
    constexpr int TPN = DIM / 4;          // threads per node
    constexpr int NPB = 256 / TPN;        // nodes per block (N_NODES % NPB == 0)
    const int tid = threadIdx.x;
    const int n   = blockIdx.x * NPB + tid / TPN;
    const int d4  = tid % TPN;
    const float4* xw4 = reinterpret_cast<const float4*>(xw);
    const int beg = rp[n];
    const int end = rp[n + 1];

    float4 a0{0,0,0,0}, a1{0,0,0,0}, a2{0,0,0,0}, a3{0,0,0,0};
    int i = beg;
    for (; i + 8 <= end; i += 8) {
        int2 e0 = ep[i],     e1 = ep[i + 1], e2 = ep[i + 2], e3 = ep[i + 3];
        int2 e4 = ep[i + 4], e5 = ep[i + 5], e6 = ep[i + 6], e7 = ep[i + 7];
        float4 v0 = xw4[(size_t)e0.x * TPN + d4];
        float4 v1 = xw4[(size_t)e1.x * TPN + d4];
        float4 v2 = xw4[(size_t)e2.x * TPN + d4];
        float4 v3 = xw4[(size_t)e3.x * TPN + d4];
        float4 v4 = xw4[(size_t)e4.x * TPN + d4];
        float4 v5 = xw4[(size_t)e5.x * TPN + d4];
        float4 v6 = xw4[(size_t)e6.x * TPN + d4];
        float4 v7 = xw4[(size_t)e7.x * TPN + d4];
        float w0 = __int_as_float(e0.y), w1 = __int_as_float(e1.y);
        float w2 = __int_as_float(e2.y), w3 = __int_as_float(e3.y);
        float w4 = __int_as_float(e4.y), w5 = __int_as_float(e5.y);
        float w6 = __int_as_float(e6.y), w7 = __int_as_float(e7.y);
        a0.x = fmaf(w0, v0.x, a0.x); a0.y = fmaf(w0, v0.y, a0.y);
        a0.z = fmaf(w0, v0.z, a0.z); a0.w = fmaf(w0, v0.w, a0.w);
        a1.x = fmaf(w1, v1.x, a1.x); a1.y = fmaf(w1, v1.y, a1.y);
        a1.z = fmaf(w1, v1.z, a1.z); a1.w = fmaf(w1, v1.w, a1.w);
        a2.x = fmaf(w2, v2.x, a2.x); a2.y = fmaf(w2, v2.y, a2.y);
        a2.z = fmaf(w2, v2.z, a2.z); a2.w = fmaf(w2, v2.w, a2.w);
        a3.x = fmaf(w3, v3.x, a3.x); a3.y = fmaf(w3, v3.y, a3.y);
        a3.z = fmaf(w3, v3.z, a3.z); a3.w = fmaf(w3, v3.w, a3.w);
        a0.x = fmaf(w4, v4.x, a0.x); a0.y = fmaf(w4, v4.y, a0.y);
        a0.z = fmaf(w4, v4.z, a0.z); a0.w = fmaf(w4, v4.w, a0.w);
        a1.x = fmaf(w5, v5.x, a1.x); a1.y = fmaf(w5, v5.y, a1.y);
        a1.z = fmaf(w5, v5.z, a1.z); a1.w = fmaf(w5, v5.w, a1.w);
        a2.x = fmaf(w6, v6.x, a2.x); a2.y = fmaf(w6, v6.y, a2.y);
        a2.z = fmaf(w6, v6.z, a2.z); a2.w = fmaf(w6, v6.w, a2.w);
        a3.x = fmaf(w7, v7.x, a3.x); a3.y = fmaf(w7, v7.y, a3.y);
        a3.z = fmaf(w7, v7.z, a3.z); a3.w = fmaf(w7, v7.w, a3.w);
    }
    for (; i + 2 <= end; i += 2) {
        int2 e0 = ep[i], e1 = ep[i + 1];
        float4 v0 = xw4[(size_t)e0.x * TPN + d4];
        float4 v1 = xw4[(size_t)e1.x * TPN + d4];
        float w0 = __int_as_float(e0.y), w1 = __int_as_float(e1.y);
        a0.x = fmaf(w0, v0.x, a0.x); a0.y = fmaf(w0, v0.y, a0.y);
        a0.z = fmaf(w0, v0.z, a0.z); a0.w = fmaf(w0, v0.w, a0.w);
        a1.x = fmaf(w1, v1.x, a1.x); a1.y = fmaf(w1, v1.y, a1.y);
        a1.z = fmaf(w1, v1.z, a1.z); a1.w = fmaf(w1, v1.w, a1.w);
    }
    if (i < end) {
        int2 e0 = ep[i];
        float4 v0 = xw4[(size_t)e0.x * TPN + d4];
        float w0 = __int_as_float(e0.y);
        a0.x = fmaf(w0, v0.x, a0.x); a0.y = fmaf(w0, v0.y, a0.y);
        a0.z = fmaf(w0, v0.z, a0.z); a0.w = fmaf(w0, v0.w, a0.w);
    }
    float4 acc;
    acc.x = (a0.x + a1.x) + (a2.x + a3.x);
    acc.y = (a0.y + a1.y) + (a2.y + a3.y);
    acc.z = (a0.z + a1.z) + (a2.z + a3.z);
    acc.w = (a0.w + a1.w) + (a2.w + a3.w);

    float di = dis[n];
    float s2 = di * di;
    float4 xn = xw4[(size_t)n * TPN + d4];
    float4 bb = reinterpret_cast<const float4*>(bias)[d4];
    float4 v;
    v.x = fmaf(s2, xn.x, acc.x) + bb.x;
    v.y = fmaf(s2, xn.y, acc.y) + bb.y;
    v.z = fmaf(s2, xn.z, acc.z) + bb.z;
    v.w = fmaf(s2, xn.w, acc.w) + bb.w;
    if (RELU) {
        v.x = fmaxf(v.x, 0.0f); v.y = fmaxf(v.y, 0.0f);
        v.z = fmaxf(v.z, 0.0f); v.w = fmaxf(v.w, 0.0f);
    }
    reinterpret_cast<float4*>(out)[(size_t)n * TPN + d4] = v;
}

extern "C" void kernel_launch(void* const* d_in, const int* in_sizes, int n_in,
                              void* d_out, int out_size, void* d_ws, size_t ws_size,
                              hipStream_t stream)
{
    const float* x    = (const float*)d_in[0];
    const int*   eidx = (const int*)  d_in[1];   // [2, N_EDGES] int32
    const float* curv = (const float*)d_in[2];   // [N_EDGES, 1]
    const float* W1   = (const float*)d_in[3];
    const float* b1   = (const float*)d_in[4];
    const float* W2   = (const float*)d_in[5];
    const float* b2   = (const float*)d_in[6];
    const float* mw1  = (const float*)d_in[7];
    const float* mb1  = (const float*)d_in[8];
    const float* mw2  = (const float*)d_in[9];
    const float* mb2  = (const float*)d_in[10];

    const int* src = eidx;
    const int* dst = eidx + N_EDGES;
    float* out = (float*)d_out;

    // --- workspace carve-out (~124 MB) ---
    char*  ws  = (char*)d_ws;
    size_t off = 0;
    auto alloc = [&](size_t bytes) -> void* {
        void* p = ws + off;
        off += (bytes + 255) & ~(size_t)255;
        return p;
    };
    float* dis   = (float*)alloc(sizeof(float) * N_NODES);
    int*   rp    = (int*)  alloc(sizeof(int) * (N_NODES + 1));
    int*   cnt4  = (int*)  alloc(sizeof(int) * NREP * N_NODES);    // [zeroed]
    int*   bsum  = (int*)  alloc(sizeof(int) * 256);
    int*   wcnt8 = (int*)  alloc(sizeof(int) * NREP * N_NODES);    // seeded by k_init_cursor
    int2*  ep    = (int2*) alloc(sizeof(int2) * N_EDGES);          // (src, ew->norm)
    float* xw    = (float*)alloc(sizeof(float) * (size_t)N_NODES * HID_DIM);
    float* h1    = (float*)alloc(sizeof(float) * (size_t)N_NODES * HID_DIM);

    hipMemsetAsync(cnt4, 0, sizeof(int) * NREP * N_NODES, stream);

    const int B = 256;
    auto cdiv = [](long long a, long long b) { return (int)((a + b - 1) / b); };

    // CSR build (contention /8, deterministic cursor bases)
    k_edge_cnt   <<<cdiv(N_EDGES, B), B, 0, stream>>>(dst, cnt4);
    k_scan_part  <<<SCAN_NB, 256, 0, stream>>>(cnt4, bsum);
    k_scan_mid   <<<1, 256, 0, stream>>>(bsum, rp);
    k_scan_final <<<SCAN_NB, 256, 0, stream>>>(cnt4, rp, bsum);
    k_init_cursor<<<cdiv(N_NODES, B), B, 0, stream>>>(cnt4, rp, wcnt8);
    k_reorder    <<<cdiv(N_EDGES, B), B, 0, stream>>>(curv, src, dst, mw1, mb1, mw2, mb2,
                                                      wcnt8, ep);
    k_deg_dis    <<<cdiv(N_NODES, B), B, 0, stream>>>(rp, ep, dis);
    k_norm       <<<cdiv(N_NODES, B), B, 0, stream>>>(rp, dis, ep);

    // layer 1
    k_gemm<IN_DIM, HID_DIM><<<N_NODES / 32, 256, 0, stream>>>(x, W1, xw);
    k_gather<HID_DIM, true><<<N_NODES / 8, 256, 0, stream>>>(rp, ep, xw, dis, b1, h1);

    // layer 2
    k_gemm<HID_DIM, OUT_DIM><<<cdiv(N_NODES, 64), 256, 0, stream>>>(h1, W2, xw);
    k_gather<OUT_DIM, false><<<N_NODES / 16, 256, 0, stream>>>(rp, ep, xw, dis, b2, out);
}

// Round 9
// 396.477 us; speedup vs baseline: 1.4511x; 1.4511x over previous
//
#include <hip/hip_runtime.h>

// ---------------------------------------------------------------------------
// LearnableCurvGCN, round 8: one random-atomic pass, bf16 xw, fatter GEMM.
//
// R7 post-mortem: NREP=8 cursor replication was a NULL (131->134us) — the
// reorder cost is the random-RMW + random-scatter op rate, not contention.
// So: eliminate one of the two random-atomic passes entirely.
//
//   pass1 k_edge_rank   : MLP -> ew[e] (coalesced); rank[e] =
//                         atomicAdd(cnt8[rep][dst],1)  [the ONLY random atomic]
//   k_scan_*            : rp = exclusive_scan(sum_r cnt8)
//   k_init_base         : base8[r][n] = rp[n] + prefix_r(cnt8[.][n])
//   pass2 k_scatter_edge: pos = base8[rep][dst] + rank[e]   (no atomics)
//                         ep[pos] = (src, ew)               (random 8B store)
//   k_deg_dis           : dis[n] = rsqrt(bucket_sum(ew)+1)
//   k_norm              : ep[i].y = dis[src]*ew*dis[n]      (CSR-style)
//   k_gemm              : xw = A @ W, fp32 math, bf16 OUTPUT (8 rows/thread)
//   k_gather            : bf16 row gather + fp32 accum, fused finalize
//
// bf16 xw halves gather FETCH (819->410MB logical). GEMMs stay fp32-math.
// ---------------------------------------------------------------------------

constexpr int N_NODES = 100000;
constexpr int N_EDGES = 1600000;
constexpr int IN_DIM  = 128;
constexpr int HID_DIM = 128;
constexpr int OUT_DIM = 64;
constexpr int NREP    = 8;

constexpr int SCAN_CHUNK = 512;
constexpr int SCAN_NB    = (N_NODES + SCAN_CHUNK - 1) / SCAN_CHUNK; // 196

// --- helpers -----------------------------------------------------------------
__device__ __forceinline__ float b2f(unsigned short u)
{
    return __uint_as_float(((unsigned int)u) << 16);
}
__device__ __forceinline__ unsigned short f2b(float f)
{
    unsigned int u = __float_as_uint(f);
    u += 0x7fffu + ((u >> 16) & 1u);     // round-to-nearest-even
    return (unsigned short)(u >> 16);
}

__device__ __forceinline__ float edge_weight_mlp(float c,
                                                 const float* __restrict__ mw1,
                                                 const float* __restrict__ mb1,
                                                 const float* __restrict__ mw2,
                                                 const float* __restrict__ mb2)
{
    float z = mb2[0];
#pragma unroll
    for (int i = 0; i < 16; ++i) {
        float h = fmaf(c, mw1[i], mb1[i]);
        h = fmaxf(h, 0.0f);
        z = fmaf(h, mw2[i], z);
    }
    float s = 1.0f / (1.0f + __expf(-z));
    return fmaf(0.9f, s, 0.1f);
}

// --- pass 1: MLP -> ew; rank within (replica, dst) ----------------------------
__global__ __launch_bounds__(256) void k_edge_rank(const float* __restrict__ curv,
                                                   const int*   __restrict__ dst,
                                                   const float* __restrict__ mw1,
                                                   const float* __restrict__ mb1,
                                                   const float* __restrict__ mw2,
                                                   const float* __restrict__ mb2,
                                                   float* __restrict__ ew,
                                                   int*   __restrict__ rank,
                                                   int*   __restrict__ cnt8)
{
    int e = blockIdx.x * blockDim.x + threadIdx.x;
    if (e >= N_EDGES) return;
    ew[e] = edge_weight_mlp(curv[e], mw1, mb1, mw2, mb2);
    int rep = blockIdx.x & (NREP - 1);
    rank[e] = atomicAdd(&cnt8[rep * N_NODES + dst[e]], 1);
}

// --- scan phase a: per-chunk reduce over replica-summed counts ----------------
__global__ __launch_bounds__(256) void k_scan_part(const int* __restrict__ cnt8,
                                                   int* __restrict__ bsum)
{
    const int b = blockIdx.x;
    const int t = threadIdx.x;
    const int i = b * SCAN_CHUNK + 2 * t;
    int s = 0;
#pragma unroll
    for (int r = 0; r < NREP; ++r) {
        if (i < N_NODES)     s += cnt8[r * N_NODES + i];
        if (i + 1 < N_NODES) s += cnt8[r * N_NODES + i + 1];
    }
#pragma unroll
    for (int o = 32; o > 0; o >>= 1) s += __shfl_down(s, o, 64);
    __shared__ int ws[4];
    if ((t & 63) == 0) ws[t >> 6] = s;
    __syncthreads();
    if (t == 0) bsum[b] = ws[0] + ws[1] + ws[2] + ws[3];
}

// --- scan phase b: scan the 196 partials; rp[N] = total ------------------------
__global__ __launch_bounds__(256) void k_scan_mid(int* __restrict__ bsum,
                                                  int* __restrict__ rp)
{
    const int t = threadIdx.x;
    int v = (t < SCAN_NB) ? bsum[t] : 0;
    __shared__ int sm[256];
    sm[t] = v;
    __syncthreads();
#pragma unroll
    for (int o = 1; o < 256; o <<= 1) {
        int u = (t >= o) ? sm[t - o] : 0;
        __syncthreads();
        sm[t] += u;
        __syncthreads();
    }
    if (t < SCAN_NB) bsum[t] = sm[t] - v;
    if (t == SCAN_NB - 1) rp[N_NODES] = sm[t];
}

// --- scan phase c: in-chunk exclusive scan + chunk offset -> rp ----------------
__global__ __launch_bounds__(256) void k_scan_final(const int* __restrict__ cnt8,
                                                    int* __restrict__ rp,
                                                    const int* __restrict__ bsum)
{
    const int b = blockIdx.x;
    const int t = threadIdx.x;
    const int i = b * SCAN_CHUNK + 2 * t;
    int c0 = 0, c1 = 0;
#pragma unroll
    for (int r = 0; r < NREP; ++r) {
        if (i < N_NODES)     c0 += cnt8[r * N_NODES + i];
        if (i + 1 < N_NODES) c1 += cnt8[r * N_NODES + i + 1];
    }
    int s = c0 + c1;
    __shared__ int sm[256];
    sm[t] = s;
    __syncthreads();
#pragma unroll
    for (int o = 1; o < 256; o <<= 1) {
        int u = (t >= o) ? sm[t - o] : 0;
        __syncthreads();
        sm[t] += u;
        __syncthreads();
    }
    int excl = sm[t] - s + bsum[b];
    if (i < N_NODES)     rp[i]     = excl;
    if (i + 1 < N_NODES) rp[i + 1] = excl + c0;
}

// --- base8[r][n] = rp[n] + prefix_r(cnt8[.][n]) --------------------------------
__global__ void k_init_base(const int* __restrict__ cnt8,
                            const int* __restrict__ rp,
                            int* __restrict__ base8)
{
    int n = blockIdx.x * blockDim.x + threadIdx.x;
    if (n >= N_NODES) return;
    int run = rp[n];
#pragma unroll
    for (int r = 0; r < NREP; ++r) {
        base8[r * N_NODES + n] = run;
        run += cnt8[r * N_NODES + n];
    }
}

// --- pass 2: atomic-free scatter into CSR order --------------------------------
__global__ __launch_bounds__(256) void k_scatter_edge(const int*   __restrict__ src,
                                                      const int*   __restrict__ dst,
                                                      const float* __restrict__ ew,
                                                      const int*   __restrict__ rank,
                                                      const int*   __restrict__ base8,
                                                      int2* __restrict__ ep)
{
    int e = blockIdx.x * blockDim.x + threadIdx.x;
    if (e >= N_EDGES) return;
    int rep = blockIdx.x & (NREP - 1);
    int pos = base8[rep * N_NODES + dst[e]] + rank[e];
    ep[pos] = make_int2(src[e], __float_as_int(ew[e]));
}

// --- dis[n] = rsqrt(bucket_sum(ew) + 1) ----------------------------------------
__global__ void k_deg_dis(const int*  __restrict__ rp,
                          const int2* __restrict__ ep,
                          float* __restrict__ dis)
{
    int n = blockIdx.x * blockDim.x + threadIdx.x;
    if (n >= N_NODES) return;
    int beg = rp[n], end = rp[n + 1];
    float s = 0.0f;
    for (int i = beg; i < end; ++i)
        s += __int_as_float(ep[i].y);
    dis[n] = rsqrtf(s + 1.0f);
}

// --- norm pass (CSR-style): ep[i].y = dis[src]*ew*dis[n] -------------------------
__global__ void k_norm(const int* __restrict__ rp,
                       const float* __restrict__ dis,
                       int2* __restrict__ ep)
{
    int n = blockIdx.x * blockDim.x + threadIdx.x;
    if (n >= N_NODES) return;
    float dn = dis[n];
    int beg = rp[n], end = rp[n + 1];
    for (int i = beg; i < end; ++i) {
        int2 e = ep[i];
        ep[i] = make_int2(e.x, __float_as_int(dis[e.x] * __int_as_float(e.y) * dn));
    }
}

// --- fp32 GEMM, bf16 output: C[N,KOUT] = A[N,KIN] @ W[KIN,KOUT] ------------------
// 8 rows x float4 cols per thread: 128 FMA per {8 A-float4 + 4 W-float4} loads.
// N_NODES % 8 == 0 and r0 % 8 == 0 -> a thread's 8 rows are all-in or all-out.
template <int KIN, int KOUT>
__global__ __launch_bounds__(256) void k_gemm(const float* __restrict__ A,
                                              const float* __restrict__ W,
                                              unsigned short* __restrict__ C)
{
    constexpr int CQ  = KOUT / 4;          // float4 column groups (32 or 16)
    constexpr int RPT = 8;                 // rows per thread
    constexpr int RPB = RPT * (256 / CQ);  // rows per block (64 or 128)
    const int tid = threadIdx.x;
    const int cq  = tid % CQ;
    const int rg  = tid / CQ;
    const int r0  = blockIdx.x * RPB + RPT * rg;
    if (r0 >= N_NODES) return;

    float4 acc[RPT];
#pragma unroll
    for (int j = 0; j < RPT; ++j) acc[j] = make_float4(0.f, 0.f, 0.f, 0.f);

#pragma unroll 2
    for (int k = 0; k < KIN; k += 4) {
        float4 xr[RPT];
#pragma unroll
        for (int j = 0; j < RPT; ++j)
            xr[j] = *reinterpret_cast<const float4*>(&A[(size_t)(r0 + j) * KIN + k]);
#pragma unroll
        for (int kk = 0; kk < 4; ++kk) {
            float4 w = *reinterpret_cast<const float4*>(&W[(k + kk) * KOUT + 4 * cq]);
#pragma unroll
            for (int j = 0; j < RPT; ++j) {
                float f = (&xr[j].x)[kk];
                acc[j].x = fmaf(f, w.x, acc[j].x);
                acc[j].y = fmaf(f, w.y, acc[j].y);
                acc[j].z = fmaf(f, w.z, acc[j].z);
                acc[j].w = fmaf(f, w.w, acc[j].w);
            }
        }
    }
#pragma unroll
    for (int j = 0; j < RPT; ++j) {
        ushort4 o;
        o.x = f2b(acc[j].x); o.y = f2b(acc[j].y);
        o.z = f2b(acc[j].z); o.w = f2b(acc[j].w);
        *reinterpret_cast<ushort4*>(&C[(size_t)(r0 + j) * KOUT + 4 * cq]) = o;
    }
}

// --- CSR gather: bf16 rows, fp32 accumulate, fused finalize ----------------------
template <int DIM, bool RELU>
__global__ __launch_bounds__(256) void k_gather(const int*  __restrict__ rp,
                                                const int2* __restrict__ ep,
                                                const unsigned short* __restrict__ xwb,
                                                const float* __restrict__ dis,
                                                const float* __restrict__ bias,
                                                float* __restrict__ out)
{
    constexpr int TPN = DIM / 4;          // threads per node (32 or 16)
    constexpr int NPB = 256 / TPN;        // nodes per block; N_NODES % NPB == 0
    const int tid = threadIdx.x;
    const int n   = blockIdx.x * NPB + tid / TPN;
    const int d4  = tid % TPN;
    const ushort4* xw4 = reinterpret_cast<const ushort4*>(xwb);
    const int beg = rp[n];
    const int end = rp[n + 1];

    float4 a0{0,0,0,0}, a1{0,0,0,0}, a2{0,0,0,0}, a3{0,0,0,0};
    int i = beg;
    for (; i + 8 <= end; i += 8) {
        int2 e0 = ep[i],     e1 = ep[i + 1], e2 = ep[i + 2], e3 = ep[i + 3];
        int2 e4 = ep[i + 4], e5 = ep[i + 5], e6 = ep[i + 6], e7 = ep[i + 7];
        ushort4 u0 = xw4[(size_t)e0.x * TPN + d4];
        ushort4 u1 = xw4[(size_t)e1.x * TPN + d4];
        ushort4 u2 = xw4[(size_t)e2.x * TPN + d4];
        ushort4 u3 = xw4[(size_t)e3.x * TPN + d4];
        ushort4 u4 = xw4[(size_t)e4.x * TPN + d4];
        ushort4 u5 = xw4[(size_t)e5.x * TPN + d4];
        ushort4 u6 = xw4[(size_t)e6.x * TPN + d4];
        ushort4 u7 = xw4[(size_t)e7.x * TPN + d4];
        float w0 = __int_as_float(e0.y), w1 = __int_as_float(e1.y);
        float w2 = __int_as_float(e2.y), w3 = __int_as_float(e3.y);
        float w4 = __int_as_float(e4.y), w5 = __int_as_float(e5.y);
        float w6 = __int_as_float(e6.y), w7 = __int_as_float(e7.y);
        a0.x = fmaf(w0, b2f(u0.x), a0.x); a0.y = fmaf(w0, b2f(u0.y), a0.y);
        a0.z = fmaf(w0, b2f(u0.z), a0.z); a0.w = fmaf(w0, b2f(u0.w), a0.w);
        a1.x = fmaf(w1, b2f(u1.x), a1.x); a1.y = fmaf(w1, b2f(u1.y), a1.y);
        a1.z = fmaf(w1, b2f(u1.z), a1.z); a1.w = fmaf(w1, b2f(u1.w), a1.w);
        a2.x = fmaf(w2, b2f(u2.x), a2.x); a2.y = fmaf(w2, b2f(u2.y), a2.y);
        a2.z = fmaf(w2, b2f(u2.z), a2.z); a2.w = fmaf(w2, b2f(u2.w), a2.w);
        a3.x = fmaf(w3, b2f(u3.x), a3.x); a3.y = fmaf(w3, b2f(u3.y), a3.y);
        a3.z = fmaf(w3, b2f(u3.z), a3.z); a3.w = fmaf(w3, b2f(u3.w), a3.w);
        a0.x = fmaf(w4, b2f(u4.x), a0.x); a0.y = fmaf(w4, b2f(u4.y), a0.y);
        a0.z = fmaf(w4, b2f(u4.z), a0.z); a0.w = fmaf(w4, b2f(u4.w), a0.w);
        a1.x = fmaf(w5, b2f(u5.x), a1.x); a1.y = fmaf(w5, b2f(u5.y), a1.y);
        a1.z = fmaf(w5, b2f(u5.z), a1.z); a1.w = fmaf(w5, b2f(u5.w), a1.w);
        a2.x = fmaf(w6, b2f(u6.x), a2.x); a2.y = fmaf(w6, b2f(u6.y), a2.y);
        a2.z = fmaf(w6, b2f(u6.z), a2.z); a2.w = fmaf(w6, b2f(u6.w), a2.w);
        a3.x = fmaf(w7, b2f(u7.x), a3.x); a3.y = fmaf(w7, b2f(u7.y), a3.y);
        a3.z = fmaf(w7, b2f(u7.z), a3.z); a3.w = fmaf(w7, b2f(u7.w), a3.w);
    }
    for (; i < end; ++i) {
        int2 e = ep[i];
        ushort4 u = xw4[(size_t)e.x * TPN + d4];
        float w = __int_as_float(e.y);
        a0.x = fmaf(w, b2f(u.x), a0.x); a0.y = fmaf(w, b2f(u.y), a0.y);
        a0.z = fmaf(w, b2f(u.z), a0.z); a0.w = fmaf(w, b2f(u.w), a0.w);
    }
    float4 acc;
    acc.x = (a0.x + a1.x) + (a2.x + a3.x);
    acc.y = (a0.y + a1.y) + (a2.y + a3.y);
    acc.z = (a0.z + a1.z) + (a2.z + a3.z);
    acc.w = (a0.w + a1.w) + (a2.w + a3.w);

    float di = dis[n];
    float s2 = di * di;
    ushort4 un = xw4[(size_t)n * TPN + d4];
    float4 bb = reinterpret_cast<const float4*>(bias)[d4];
    float4 v;
    v.x = fmaf(s2, b2f(un.x), acc.x) + bb.x;
    v.y = fmaf(s2, b2f(un.y), acc.y) + bb.y;
    v.z = fmaf(s2, b2f(un.z), acc.z) + bb.z;
    v.w = fmaf(s2, b2f(un.w), acc.w) + bb.w;
    if (RELU) {
        v.x = fmaxf(v.x, 0.0f); v.y = fmaxf(v.y, 0.0f);
        v.z = fmaxf(v.z, 0.0f); v.w = fmaxf(v.w, 0.0f);
    }
    reinterpret_cast<float4*>(out)[(size_t)n * TPN + d4] = v;
}

extern "C" void kernel_launch(void* const* d_in, const int* in_sizes, int n_in,
                              void* d_out, int out_size, void* d_ws, size_t ws_size,
                              hipStream_t stream)
{
    const float* x    = (const float*)d_in[0];
    const int*   eidx = (const int*)  d_in[1];   // [2, N_EDGES] int32
    const float* curv = (const float*)d_in[2];   // [N_EDGES, 1]
    const float* W1   = (const float*)d_in[3];
    const float* b1   = (const float*)d_in[4];
    const float* W2   = (const float*)d_in[5];
    const float* b2   = (const float*)d_in[6];
    const float* mw1  = (const float*)d_in[7];
    const float* mb1  = (const float*)d_in[8];
    const float* mw2  = (const float*)d_in[9];
    const float* mb2  = (const float*)d_in[10];

    const int* src = eidx;
    const int* dst = eidx + N_EDGES;
    float* out = (float*)d_out;

    // --- workspace carve-out (~110 MB) ---
    char*  ws  = (char*)d_ws;
    size_t off = 0;
    auto alloc = [&](size_t bytes) -> void* {
        void* p = ws + off;
        off += (bytes + 255) & ~(size_t)255;
        return p;
    };
    float* dis   = (float*)alloc(sizeof(float) * N_NODES);
    int*   rp    = (int*)  alloc(sizeof(int) * (N_NODES + 1));
    int*   cnt8  = (int*)  alloc(sizeof(int) * NREP * N_NODES);       // [zeroed]
    int*   bsum  = (int*)  alloc(sizeof(int) * 256);
    int*   base8 = (int*)  alloc(sizeof(int) * NREP * N_NODES);
    float* ew    = (float*)alloc(sizeof(float) * N_EDGES);
    int*   rank  = (int*)  alloc(sizeof(int) * N_EDGES);
    int2*  ep    = (int2*) alloc(sizeof(int2) * N_EDGES);             // (src, ew->norm)
    unsigned short* xwb = (unsigned short*)alloc(sizeof(unsigned short) * (size_t)N_NODES * HID_DIM);
    float* h1    = (float*)alloc(sizeof(float) * (size_t)N_NODES * HID_DIM);

    hipMemsetAsync(cnt8, 0, sizeof(int) * NREP * N_NODES, stream);

    const int B = 256;
    auto cdiv = [](long long a, long long b) { return (int)((a + b - 1) / b); };

    // CSR build: one random-atomic pass (rank), one atomic-free scatter
    k_edge_rank   <<<cdiv(N_EDGES, B), B, 0, stream>>>(curv, dst, mw1, mb1, mw2, mb2,
                                                       ew, rank, cnt8);
    k_scan_part   <<<SCAN_NB, 256, 0, stream>>>(cnt8, bsum);
    k_scan_mid    <<<1, 256, 0, stream>>>(bsum, rp);
    k_scan_final  <<<SCAN_NB, 256, 0, stream>>>(cnt8, rp, bsum);
    k_init_base   <<<cdiv(N_NODES, B), B, 0, stream>>>(cnt8, rp, base8);
    k_scatter_edge<<<cdiv(N_EDGES, B), B, 0, stream>>>(src, dst, ew, rank, base8, ep);
    k_deg_dis     <<<cdiv(N_NODES, B), B, 0, stream>>>(rp, ep, dis);
    k_norm        <<<cdiv(N_NODES, B), B, 0, stream>>>(rp, dis, ep);

    // layer 1: xw1(bf16) = x@W1; h1(fp32) = relu(gather + self + b1)
    k_gemm<IN_DIM, HID_DIM><<<cdiv(N_NODES, 64), 256, 0, stream>>>(x, W1, xwb);
    k_gather<HID_DIM, true><<<N_NODES / 8, 256, 0, stream>>>(rp, ep, xwb, dis, b1, h1);

    // layer 2: xw2(bf16) = h1@W2; out(fp32) = gather + self + b2
    k_gemm<HID_DIM, OUT_DIM><<<cdiv(N_NODES, 128), 256, 0, stream>>>(h1, W2, xwb);
    k_gather<OUT_DIM, false><<<N_NODES / 16, 256, 0, stream>>>(rp, ep, xwb, dis, b2, out);
}

// Round 10
// 300.600 us; speedup vs baseline: 1.9140x; 1.3190x over previous
//
#include <hip/hip_runtime.h>

// ---------------------------------------------------------------------------
// LearnableCurvGCN, round 9: MFMA GEMMs.
//
// R8 counters: k_gemm<128,128> was #1 at 122us, VALUBusy 21%, MfmaUtil 0 —
// fp32 vector GEMM at 17% of the 157TF vector ceiling while the 2.5PF matrix
// cores idle. Both GEMMs now use mfma_f32_16x16x32_bf16:
//   - k_cvt     : x fp32 -> bf16 (xb), one coalesced pass
//   - k_prepack : W (fp32) -> per-lane bf16 fragment layout
//                 (lane l: col = l&15, k-octet = l>>4; m89-verified mapping)
//   - k_gemm_mfma<KIN,KOUT>: wave computes 16 rows x KOUT; acc[nt] += A*B
//   - gather1 emits bf16 h1 directly (feeds GEMM2, halves its own writes)
// Edge/CSR pipeline unchanged from R8 (1 random-atomic pass + free scatter).
// ---------------------------------------------------------------------------

constexpr int N_NODES = 100000;
constexpr int N_EDGES = 1600000;
constexpr int IN_DIM  = 128;
constexpr int HID_DIM = 128;
constexpr int OUT_DIM = 64;
constexpr int NREP    = 8;

constexpr int SCAN_CHUNK = 512;
constexpr int SCAN_NB    = (N_NODES + SCAN_CHUNK - 1) / SCAN_CHUNK; // 196

using bf16x8 = __attribute__((ext_vector_type(8))) short;   // 8 bf16 (4 VGPRs)
using f32x4  = __attribute__((ext_vector_type(4))) float;   // MFMA C/D frag

// --- helpers -----------------------------------------------------------------
__device__ __forceinline__ float b2f(unsigned short u)
{
    return __uint_as_float(((unsigned int)u) << 16);
}
__device__ __forceinline__ unsigned short f2b(float f)
{
    unsigned int u = __float_as_uint(f);
    u += 0x7fffu + ((u >> 16) & 1u);     // round-to-nearest-even
    return (unsigned short)(u >> 16);
}

__device__ __forceinline__ float edge_weight_mlp(float c,
                                                 const float* __restrict__ mw1,
                                                 const float* __restrict__ mb1,
                                                 const float* __restrict__ mw2,
                                                 const float* __restrict__ mb2)
{
    float z = mb2[0];
#pragma unroll
    for (int i = 0; i < 16; ++i) {
        float h = fmaf(c, mw1[i], mb1[i]);
        h = fmaxf(h, 0.0f);
        z = fmaf(h, mw2[i], z);
    }
    float s = 1.0f / (1.0f + __expf(-z));
    return fmaf(0.9f, s, 0.1f);
}

// --- pass 1: MLP -> ew; rank within (replica, dst) ----------------------------
__global__ __launch_bounds__(256) void k_edge_rank(const float* __restrict__ curv,
                                                   const int*   __restrict__ dst,
                                                   const float* __restrict__ mw1,
                                                   const float* __restrict__ mb1,
                                                   const float* __restrict__ mw2,
                                                   const float* __restrict__ mb2,
                                                   float* __restrict__ ew,
                                                   int*   __restrict__ rank,
                                                   int*   __restrict__ cnt8)
{
    int e = blockIdx.x * blockDim.x + threadIdx.x;
    if (e >= N_EDGES) return;
    ew[e] = edge_weight_mlp(curv[e], mw1, mb1, mw2, mb2);
    int rep = blockIdx.x & (NREP - 1);
    rank[e] = atomicAdd(&cnt8[rep * N_NODES + dst[e]], 1);
}

// --- scan phase a -------------------------------------------------------------
__global__ __launch_bounds__(256) void k_scan_part(const int* __restrict__ cnt8,
                                                   int* __restrict__ bsum)
{
    const int b = blockIdx.x;
    const int t = threadIdx.x;
    const int i = b * SCAN_CHUNK + 2 * t;
    int s = 0;
#pragma unroll
    for (int r = 0; r < NREP; ++r) {
        if (i < N_NODES)     s += cnt8[r * N_NODES + i];
        if (i + 1 < N_NODES) s += cnt8[r * N_NODES + i + 1];
    }
#pragma unroll
    for (int o = 32; o > 0; o >>= 1) s += __shfl_down(s, o, 64);
    __shared__ int ws[4];
    if ((t & 63) == 0) ws[t >> 6] = s;
    __syncthreads();
    if (t == 0) bsum[b] = ws[0] + ws[1] + ws[2] + ws[3];
}

// --- scan phase b -------------------------------------------------------------
__global__ __launch_bounds__(256) void k_scan_mid(int* __restrict__ bsum,
                                                  int* __restrict__ rp)
{
    const int t = threadIdx.x;
    int v = (t < SCAN_NB) ? bsum[t] : 0;
    __shared__ int sm[256];
    sm[t] = v;
    __syncthreads();
#pragma unroll
    for (int o = 1; o < 256; o <<= 1) {
        int u = (t >= o) ? sm[t - o] : 0;
        __syncthreads();
        sm[t] += u;
        __syncthreads();
    }
    if (t < SCAN_NB) bsum[t] = sm[t] - v;
    if (t == SCAN_NB - 1) rp[N_NODES] = sm[t];
}

// --- scan phase c -------------------------------------------------------------
__global__ __launch_bounds__(256) void k_scan_final(const int* __restrict__ cnt8,
                                                    int* __restrict__ rp,
                                                    const int* __restrict__ bsum)
{
    const int b = blockIdx.x;
    const int t = threadIdx.x;
    const int i = b * SCAN_CHUNK + 2 * t;
    int c0 = 0, c1 = 0;
#pragma unroll
    for (int r = 0; r < NREP; ++r) {
        if (i < N_NODES)     c0 += cnt8[r * N_NODES + i];
        if (i + 1 < N_NODES) c1 += cnt8[r * N_NODES + i + 1];
    }
    int s = c0 + c1;
    __shared__ int sm[256];
    sm[t] = s;
    __syncthreads();
#pragma unroll
    for (int o = 1; o < 256; o <<= 1) {
        int u = (t >= o) ? sm[t - o] : 0;
        __syncthreads();
        sm[t] += u;
        __syncthreads();
    }
    int excl = sm[t] - s + bsum[b];
    if (i < N_NODES)     rp[i]     = excl;
    if (i + 1 < N_NODES) rp[i + 1] = excl + c0;
}

// --- base8[r][n] = rp[n] + prefix_r(cnt8[.][n]) --------------------------------
__global__ void k_init_base(const int* __restrict__ cnt8,
                            const int* __restrict__ rp,
                            int* __restrict__ base8)
{
    int n = blockIdx.x * blockDim.x + threadIdx.x;
    if (n >= N_NODES) return;
    int run = rp[n];
#pragma unroll
    for (int r = 0; r < NREP; ++r) {
        base8[r * N_NODES + n] = run;
        run += cnt8[r * N_NODES + n];
    }
}

// --- pass 2: atomic-free scatter into CSR order --------------------------------
__global__ __launch_bounds__(256) void k_scatter_edge(const int*   __restrict__ src,
                                                      const int*   __restrict__ dst,
                                                      const float* __restrict__ ew,
                                                      const int*   __restrict__ rank,
                                                      const int*   __restrict__ base8,
                                                      int2* __restrict__ ep)
{
    int e = blockIdx.x * blockDim.x + threadIdx.x;
    if (e >= N_EDGES) return;
    int rep = blockIdx.x & (NREP - 1);
    int pos = base8[rep * N_NODES + dst[e]] + rank[e];
    ep[pos] = make_int2(src[e], __float_as_int(ew[e]));
}

// --- dis[n] = rsqrt(bucket_sum(ew) + 1) ----------------------------------------
__global__ void k_deg_dis(const int*  __restrict__ rp,
                          const int2* __restrict__ ep,
                          float* __restrict__ dis)
{
    int n = blockIdx.x * blockDim.x + threadIdx.x;
    if (n >= N_NODES) return;
    int beg = rp[n], end = rp[n + 1];
    float s = 0.0f;
    for (int i = beg; i < end; ++i)
        s += __int_as_float(ep[i].y);
    dis[n] = rsqrtf(s + 1.0f);
}

// --- norm pass (CSR-style): ep[i].y = dis[src]*ew*dis[n] -------------------------
__global__ void k_norm(const int* __restrict__ rp,
                       const float* __restrict__ dis,
                       int2* __restrict__ ep)
{
    int n = blockIdx.x * blockDim.x + threadIdx.x;
    if (n >= N_NODES) return;
    float dn = dis[n];
    int beg = rp[n], end = rp[n + 1];
    for (int i = beg; i < end; ++i) {
        int2 e = ep[i];
        ep[i] = make_int2(e.x, __float_as_int(dis[e.x] * __int_as_float(e.y) * dn));
    }
}

// --- fp32 -> bf16 conversion (8 elems/thread, coalesced) -------------------------
__global__ __launch_bounds__(256) void k_cvt(const float4* __restrict__ in,
                                             uint4* __restrict__ out,
                                             int n8)
{
    int i = blockIdx.x * blockDim.x + threadIdx.x;
    if (i >= n8) return;
    float4 a = in[2 * i];
    float4 b = in[2 * i + 1];
    uint4 o;
    o.x = (unsigned)f2b(a.x) | ((unsigned)f2b(a.y) << 16);
    o.y = (unsigned)f2b(a.z) | ((unsigned)f2b(a.w) << 16);
    o.z = (unsigned)f2b(b.x) | ((unsigned)f2b(b.y) << 16);
    o.w = (unsigned)f2b(b.z) | ((unsigned)f2b(b.w) << 16);
    out[i] = o;
}

// --- prepack W into B-fragment layout: slot(nt,ks,lane) = 8 bf16 -----------------
// lane l supplies B[k][col] with col = nt*16 + (l&15), k = ks*32 + (l>>4)*8 + j.
template <int KIN, int KOUT>
__global__ __launch_bounds__(256) void k_prepack(const float* __restrict__ W,
                                                 unsigned short* __restrict__ wp)
{
    constexpr int KS = KIN / 32;
    constexpr int NSLOT = (KOUT / 16) * KS * 64;
    int idx = blockIdx.x * blockDim.x + threadIdx.x;
    if (idx >= NSLOT) return;
    int l  = idx & 63;
    int t  = idx >> 6;
    int ks = t % KS;
    int nt = t / KS;
    int col = nt * 16 + (l & 15);
    int k0  = ks * 32 + (l >> 4) * 8;
    unsigned short o[8];
#pragma unroll
    for (int j = 0; j < 8; ++j)
        o[j] = f2b(W[(k0 + j) * KOUT + col]);
    *reinterpret_cast<uint4*>(&wp[(size_t)idx * 8]) = *reinterpret_cast<uint4*>(o);
}

// --- MFMA GEMM: C[N,KOUT](bf16) = A[N,KIN](bf16) @ W ------------------------------
// One wave per 16 rows; acc[nt] accumulates over all K (the K-loop recipe).
template <int KIN, int KOUT>
__global__ __launch_bounds__(256) void k_gemm_mfma(const unsigned short* __restrict__ Ab,
                                                   const unsigned short* __restrict__ Wp,
                                                   unsigned short* __restrict__ C)
{
    constexpr int NT = KOUT / 16;
    constexpr int KS = KIN / 32;
    const int tid  = threadIdx.x;
    const int lane = tid & 63;
    const int wave = blockIdx.x * (blockDim.x >> 6) + (tid >> 6);
    const int row0 = wave * 16;
    if (row0 >= N_NODES) return;

    f32x4 acc[NT];
#pragma unroll
    for (int nt = 0; nt < NT; ++nt)
        acc[nt] = f32x4{0.f, 0.f, 0.f, 0.f};

    const int arow = row0 + (lane & 15);
    const int koff = (lane >> 4) * 8;
#pragma unroll
    for (int ks = 0; ks < KS; ++ks) {
        bf16x8 a = *reinterpret_cast<const bf16x8*>(Ab + (size_t)arow * KIN + ks * 32 + koff);
#pragma unroll
        for (int nt = 0; nt < NT; ++nt) {
            bf16x8 b = *reinterpret_cast<const bf16x8*>(Wp + ((size_t)(nt * KS + ks) * 64 + lane) * 8);
            acc[nt] = __builtin_amdgcn_mfma_f32_16x16x32_bf16(a, b, acc[nt], 0, 0, 0);
        }
    }

    // C/D layout (m89-verified): col = lane&15, row = (lane>>4)*4 + r
    const int r0 = row0 + ((lane >> 4) << 2);
    const int c0 = lane & 15;
#pragma unroll
    for (int nt = 0; nt < NT; ++nt) {
#pragma unroll
        for (int r = 0; r < 4; ++r)
            C[(size_t)(r0 + r) * KOUT + nt * 16 + c0] = f2b(acc[nt][r]);
    }
}

// --- CSR gather: bf16 rows, fp32 accumulate, fused finalize ----------------------
template <int DIM, bool RELU, bool OBF16>
__global__ __launch_bounds__(256) void k_gather(const int*  __restrict__ rp,
                                                const int2* __restrict__ ep,
                                                const unsigned short* __restrict__ xwb,
                                                const float* __restrict__ dis,
                                                const float* __restrict__ bias,
                                                void* __restrict__ out)
{
    constexpr int TPN = DIM / 4;          // threads per node (32 or 16)
    constexpr int NPB = 256 / TPN;        // nodes per block; N_NODES % NPB == 0
    const int tid = threadIdx.x;
    const int n   = blockIdx.x * NPB + tid / TPN;
    const int d4  = tid % TPN;
    const ushort4* xw4 = reinterpret_cast<const ushort4*>(xwb);
    const int beg = rp[n];
    const int end = rp[n + 1];

    float4 a0{0,0,0,0}, a1{0,0,0,0}, a2{0,0,0,0}, a3{0,0,0,0};
    int i = beg;
    for (; i + 8 <= end; i += 8) {
        int2 e0 = ep[i],     e1 = ep[i + 1], e2 = ep[i + 2], e3 = ep[i + 3];
        int2 e4 = ep[i + 4], e5 = ep[i + 5], e6 = ep[i + 6], e7 = ep[i + 7];
        ushort4 u0 = xw4[(size_t)e0.x * TPN + d4];
        ushort4 u1 = xw4[(size_t)e1.x * TPN + d4];
        ushort4 u2 = xw4[(size_t)e2.x * TPN + d4];
        ushort4 u3 = xw4[(size_t)e3.x * TPN + d4];
        ushort4 u4 = xw4[(size_t)e4.x * TPN + d4];
        ushort4 u5 = xw4[(size_t)e5.x * TPN + d4];
        ushort4 u6 = xw4[(size_t)e6.x * TPN + d4];
        ushort4 u7 = xw4[(size_t)e7.x * TPN + d4];
        float w0 = __int_as_float(e0.y), w1 = __int_as_float(e1.y);
        float w2 = __int_as_float(e2.y), w3 = __int_as_float(e3.y);
        float w4 = __int_as_float(e4.y), w5 = __int_as_float(e5.y);
        float w6 = __int_as_float(e6.y), w7 = __int_as_float(e7.y);
        a0.x = fmaf(w0, b2f(u0.x), a0.x); a0.y = fmaf(w0, b2f(u0.y), a0.y);
        a0.z = fmaf(w0, b2f(u0.z), a0.z); a0.w = fmaf(w0, b2f(u0.w), a0.w);
        a1.x = fmaf(w1, b2f(u1.x), a1.x); a1.y = fmaf(w1, b2f(u1.y), a1.y);
        a1.z = fmaf(w1, b2f(u1.z), a1.z); a1.w = fmaf(w1, b2f(u1.w), a1.w);
        a2.x = fmaf(w2, b2f(u2.x), a2.x); a2.y = fmaf(w2, b2f(u2.y), a2.y);
        a2.z = fmaf(w2, b2f(u2.z), a2.z); a2.w = fmaf(w2, b2f(u2.w), a2.w);
        a3.x = fmaf(w3, b2f(u3.x), a3.x); a3.y = fmaf(w3, b2f(u3.y), a3.y);
        a3.z = fmaf(w3, b2f(u3.z), a3.z); a3.w = fmaf(w3, b2f(u3.w), a3.w);
        a0.x = fmaf(w4, b2f(u4.x), a0.x); a0.y = fmaf(w4, b2f(u4.y), a0.y);
        a0.z = fmaf(w4, b2f(u4.z), a0.z); a0.w = fmaf(w4, b2f(u4.w), a0.w);
        a1.x = fmaf(w5, b2f(u5.x), a1.x); a1.y = fmaf(w5, b2f(u5.y), a1.y);
        a1.z = fmaf(w5, b2f(u5.z), a1.z); a1.w = fmaf(w5, b2f(u5.w), a1.w);
        a2.x = fmaf(w6, b2f(u6.x), a2.x); a2.y = fmaf(w6, b2f(u6.y), a2.y);
        a2.z = fmaf(w6, b2f(u6.z), a2.z); a2.w = fmaf(w6, b2f(u6.w), a2.w);
        a3.x = fmaf(w7, b2f(u7.x), a3.x); a3.y = fmaf(w7, b2f(u7.y), a3.y);
        a3.z = fmaf(w7, b2f(u7.z), a3.z); a3.w = fmaf(w7, b2f(u7.w), a3.w);
    }
    for (; i < end; ++i) {
        int2 e = ep[i];
        ushort4 u = xw4[(size_t)e.x * TPN + d4];
        float w = __int_as_float(e.y);
        a0.x = fmaf(w, b2f(u.x), a0.x); a0.y = fmaf(w, b2f(u.y), a0.y);
        a0.z = fmaf(w, b2f(u.z), a0.z); a0.w = fmaf(w, b2f(u.w), a0.w);
    }
    float4 acc;
    acc.x = (a0.x + a1.x) + (a2.x + a3.x);
    acc.y = (a0.y + a1.y) + (a2.y + a3.y);
    acc.z = (a0.z + a1.z) + (a2.z + a3.z);
    acc.w = (a0.w + a1.w) + (a2.w + a3.w);

    float di = dis[n];
    float s2 = di * di;
    ushort4 un = xw4[(size_t)n * TPN + d4];
    float4 bb = reinterpret_cast<const float4*>(bias)[d4];
    float4 v;
    v.x = fmaf(s2, b2f(un.x), acc.x) + bb.x;
    v.y = fmaf(s2, b2f(un.y), acc.y) + bb.y;
    v.z = fmaf(s2, b2f(un.z), acc.z) + bb.z;
    v.w = fmaf(s2, b2f(un.w), acc.w) + bb.w;
    if (RELU) {
        v.x = fmaxf(v.x, 0.0f); v.y = fmaxf(v.y, 0.0f);
        v.z = fmaxf(v.z, 0.0f); v.w = fmaxf(v.w, 0.0f);
    }
    if (OBF16) {
        ushort4 o;
        o.x = f2b(v.x); o.y = f2b(v.y); o.z = f2b(v.z); o.w = f2b(v.w);
        reinterpret_cast<ushort4*>(out)[(size_t)n * TPN + d4] = o;
    } else {
        reinterpret_cast<float4*>(out)[(size_t)n * TPN + d4] = v;
    }
}

extern "C" void kernel_launch(void* const* d_in, const int* in_sizes, int n_in,
                              void* d_out, int out_size, void* d_ws, size_t ws_size,
                              hipStream_t stream)
{
    const float* x    = (const float*)d_in[0];
    const int*   eidx = (const int*)  d_in[1];   // [2, N_EDGES] int32
    const float* curv = (const float*)d_in[2];   // [N_EDGES, 1]
    const float* W1   = (const float*)d_in[3];
    const float* b1   = (const float*)d_in[4];
    const float* W2   = (const float*)d_in[5];
    const float* b2   = (const float*)d_in[6];
    const float* mw1  = (const float*)d_in[7];
    const float* mb1  = (const float*)d_in[8];
    const float* mw2  = (const float*)d_in[9];
    const float* mb2  = (const float*)d_in[10];

    const int* src = eidx;
    const int* dst = eidx + N_EDGES;
    float* out = (float*)d_out;

    // --- workspace carve-out (~110 MB) ---
    char*  ws  = (char*)d_ws;
    size_t off = 0;
    auto alloc = [&](size_t bytes) -> void* {
        void* p = ws + off;
        off += (bytes + 255) & ~(size_t)255;
        return p;
    };
    float* dis   = (float*)alloc(sizeof(float) * N_NODES);
    int*   rp    = (int*)  alloc(sizeof(int) * (N_NODES + 1));
    int*   cnt8  = (int*)  alloc(sizeof(int) * NREP * N_NODES);       // [zeroed]
    int*   bsum  = (int*)  alloc(sizeof(int) * 256);
    int*   base8 = (int*)  alloc(sizeof(int) * NREP * N_NODES);
    float* ew    = (float*)alloc(sizeof(float) * N_EDGES);
    int*   rank  = (int*)  alloc(sizeof(int) * N_EDGES);
    int2*  ep    = (int2*) alloc(sizeof(int2) * N_EDGES);             // (src, ew->norm)
    unsigned short* xb  = (unsigned short*)alloc(sizeof(unsigned short) * (size_t)N_NODES * IN_DIM);
    unsigned short* xwb = (unsigned short*)alloc(sizeof(unsigned short) * (size_t)N_NODES * HID_DIM);
    unsigned short* h1b = (unsigned short*)alloc(sizeof(unsigned short) * (size_t)N_NODES * HID_DIM);
    unsigned short* wp1 = (unsigned short*)alloc(sizeof(unsigned short) * (HID_DIM / 16) * (IN_DIM / 32) * 64 * 8);
    unsigned short* wp2 = (unsigned short*)alloc(sizeof(unsigned short) * (OUT_DIM / 16) * (HID_DIM / 32) * 64 * 8);

    hipMemsetAsync(cnt8, 0, sizeof(int) * NREP * N_NODES, stream);

    const int B = 256;
    auto cdiv = [](long long a, long long b) { return (int)((a + b - 1) / b); };

    // CSR build: one random-atomic pass (rank), one atomic-free scatter
    k_edge_rank   <<<cdiv(N_EDGES, B), B, 0, stream>>>(curv, dst, mw1, mb1, mw2, mb2,
                                                       ew, rank, cnt8);
    k_scan_part   <<<SCAN_NB, 256, 0, stream>>>(cnt8, bsum);
    k_scan_mid    <<<1, 256, 0, stream>>>(bsum, rp);
    k_scan_final  <<<SCAN_NB, 256, 0, stream>>>(cnt8, rp, bsum);
    k_init_base   <<<cdiv(N_NODES, B), B, 0, stream>>>(cnt8, rp, base8);
    k_scatter_edge<<<cdiv(N_EDGES, B), B, 0, stream>>>(src, dst, ew, rank, base8, ep);
    k_deg_dis     <<<cdiv(N_NODES, B), B, 0, stream>>>(rp, ep, dis);
    k_norm        <<<cdiv(N_NODES, B), B, 0, stream>>>(rp, dis, ep);

    // bf16 conversions / weight prepack (overlap-friendly, all tiny except cvt)
    k_cvt<<<cdiv((size_t)N_NODES * IN_DIM / 8, B), B, 0, stream>>>(
        (const float4*)x, (uint4*)xb, (int)((size_t)N_NODES * IN_DIM / 8));
    k_prepack<IN_DIM, HID_DIM><<<cdiv((HID_DIM/16)*(IN_DIM/32)*64, B), B, 0, stream>>>(W1, wp1);
    k_prepack<HID_DIM, OUT_DIM><<<cdiv((OUT_DIM/16)*(HID_DIM/32)*64, B), B, 0, stream>>>(W2, wp2);

    const int GEMM_GRID = cdiv(N_NODES / 16, 4);   // 4 waves/block, 16 rows/wave

    // layer 1: xw1(bf16) = x@W1 (MFMA); h1(bf16) = relu(gather + self + b1)
    k_gemm_mfma<IN_DIM, HID_DIM><<<GEMM_GRID, 256, 0, stream>>>(xb, wp1, xwb);
    k_gather<HID_DIM, true, true><<<N_NODES / 8, 256, 0, stream>>>(rp, ep, xwb, dis, b1, h1b);

    // layer 2: xw2(bf16) = h1@W2 (MFMA); out(fp32) = gather + self + b2
    k_gemm_mfma<HID_DIM, OUT_DIM><<<GEMM_GRID, 256, 0, stream>>>(h1b, wp2, xwb);
    k_gather<OUT_DIM, false, false><<<N_NODES / 16, 256, 0, stream>>>(rp, ep, xwb, dis, b2, out);
}

// Round 11
// 228.112 us; speedup vs baseline: 2.5222x; 1.3178x over previous
//
#include <hip/hip_runtime.h>

// ---------------------------------------------------------------------------
// LearnableCurvGCN, round 10: bucketed counting sort + dis-premultiplied xw.
//
// R9 counters: gather<128> #1 (75us, FETCH 192MB); CSR chain (edge_rank +
// scatter_edge + deg_dis + norm) ~140us of random-address op-rate floor.
//
// New CSR build (no global atomics after the histogram, far less random I/O):
//   k_hist        : per-block LDS histogram of dst>>8 (391 coarse buckets);
//                   row stored to blockHist; totals atomically to gcnt
//   k_scan_buckets: bucketBase = exclusive_scan(gcnt)
//   k_colscan     : blockHist[b][j] -> per-block write base (deterministic)
//   k_partition   : MLP(curv)->ew; LDS cursor -> ep_tmp[(src|dl<<17), ew]
//                   grouped by coarse bucket
//   k_bucket_sort : per bucket (=256 consecutive nodes, ALL their edges):
//                   LDS count + deg sum -> local scan -> rp, dis, final ep
//
// norm pass eliminated: GEMM epilogue scales row n by dis[n] (xws = dis*xw),
// gather computes out = dis[n]*(sum ew*xws[src] + xws[n]) + b  (identical
// math: norm*xw[src] = dis[n]*ew*(dis[src]*xw[src])).
// Gather: uint4 (8 bf16) per thread, 8-deep unroll.
// ---------------------------------------------------------------------------

constexpr int N_NODES = 100000;
constexpr int N_EDGES = 1600000;
constexpr int IN_DIM  = 128;
constexpr int HID_DIM = 128;
constexpr int OUT_DIM = 64;

constexpr int RANGE = 256;                            // nodes per bucket
constexpr int NBUK  = (N_NODES + RANGE - 1) / RANGE;  // 391
constexpr int EPB   = 4096;                           // edges per partition block
constexpr int NPART = (N_EDGES + EPB - 1) / EPB;      // 391

using bf16x8 = __attribute__((ext_vector_type(8))) short;
using f32x4  = __attribute__((ext_vector_type(4))) float;

// --- helpers -----------------------------------------------------------------
__device__ __forceinline__ unsigned short f2b(float f)
{
    unsigned int u = __float_as_uint(f);
    u += 0x7fffu + ((u >> 16) & 1u);     // round-to-nearest-even
    return (unsigned short)(u >> 16);
}

__device__ __forceinline__ float edge_weight_mlp(float c,
                                                 const float* __restrict__ mw1,
                                                 const float* __restrict__ mb1,
                                                 const float* __restrict__ mw2,
                                                 const float* __restrict__ mb2)
{
    float z = mb2[0];
#pragma unroll
    for (int i = 0; i < 16; ++i) {
        float h = fmaf(c, mw1[i], mb1[i]);
        h = fmaxf(h, 0.0f);
        z = fmaf(h, mw2[i], z);
    }
    float s = 1.0f / (1.0f + __expf(-z));
    return fmaf(0.9f, s, 0.1f);
}

// --- 1. coarse histogram: blockHist[block][bucket], gcnt[bucket] --------------
__global__ __launch_bounds__(512) void k_hist(const int* __restrict__ dst,
                                              int* __restrict__ blockHist,
                                              int* __restrict__ gcnt)
{
    __shared__ int hist[NBUK];
    const int tid = threadIdx.x;
    for (int i = tid; i < NBUK; i += 512) hist[i] = 0;
    __syncthreads();
    const int base = blockIdx.x * EPB;
    const int n = min(EPB, N_EDGES - base);
    for (int i = tid; i < n; i += 512)
        atomicAdd(&hist[dst[base + i] >> 8], 1);
    __syncthreads();
    for (int i = tid; i < NBUK; i += 512) {
        int h = hist[i];
        blockHist[(size_t)blockIdx.x * NBUK + i] = h;
        if (h) atomicAdd(&gcnt[i], h);
    }
}

// --- 2. bucketBase = exclusive_scan(gcnt); bucketBase[NBUK] = total -----------
__global__ __launch_bounds__(512) void k_scan_buckets(const int* __restrict__ gcnt,
                                                      int* __restrict__ bucketBase)
{
    __shared__ int sm[512];
    const int t = threadIdx.x;
    int v = (t < NBUK) ? gcnt[t] : 0;
    sm[t] = v;
    __syncthreads();
#pragma unroll
    for (int o = 1; o < 512; o <<= 1) {
        int u = (t >= o) ? sm[t - o] : 0;
        __syncthreads();
        sm[t] += u;
        __syncthreads();
    }
    if (t < NBUK) bucketBase[t] = sm[t] - v;
    if (t == NBUK - 1) bucketBase[NBUK] = sm[t];
}

// --- 3. column scan: blockHist[b][j] -> deterministic per-block write base ----
__global__ __launch_bounds__(256) void k_colscan(int* __restrict__ blockHist,
                                                 const int* __restrict__ bucketBase)
{
    int j = blockIdx.x * blockDim.x + threadIdx.x;
    if (j >= NBUK) return;
    int run = bucketBase[j];
    for (int b = 0; b < NPART; ++b) {
        size_t idx = (size_t)b * NBUK + j;
        int t = blockHist[idx];
        blockHist[idx] = run;
        run += t;
    }
}

// --- 4. partition edges into coarse-bucket segments ----------------------------
__global__ __launch_bounds__(512) void k_partition(const float* __restrict__ curv,
                                                   const int*   __restrict__ src,
                                                   const int*   __restrict__ dst,
                                                   const float* __restrict__ mw1,
                                                   const float* __restrict__ mb1,
                                                   const float* __restrict__ mw2,
                                                   const float* __restrict__ mb2,
                                                   const int*   __restrict__ blockHist,
                                                   int2* __restrict__ ep_tmp)
{
    __shared__ int cur[NBUK];
    const int tid = threadIdx.x;
    for (int i = tid; i < NBUK; i += 512)
        cur[i] = blockHist[(size_t)blockIdx.x * NBUK + i];
    __syncthreads();
    const int base = blockIdx.x * EPB;
    const int n = min(EPB, N_EDGES - base);
    for (int i = tid; i < n; i += 512) {
        int e = base + i;
        int d = dst[e];
        float w = edge_weight_mlp(curv[e], mw1, mb1, mw2, mb2);
        int pos = atomicAdd(&cur[d >> 8], 1);
        int meta = src[e] | ((d & (RANGE - 1)) << 17);   // src<2^17, dl<256
        ep_tmp[pos] = make_int2(meta, __float_as_int(w));
    }
}

// --- 5. per-bucket counting sort + deg + dis + rp -------------------------------
__global__ __launch_bounds__(256) void k_bucket_sort(const int2* __restrict__ ep_tmp,
                                                     const int*  __restrict__ bucketBase,
                                                     int2* __restrict__ ep,
                                                     int*  __restrict__ rp,
                                                     float* __restrict__ dis)
{
    const int b   = blockIdx.x;
    const int tid = threadIdx.x;
    const int base  = bucketBase[b];
    const int nE    = bucketBase[b + 1] - base;
    const int node0 = b * RANGE;
    const int nNodes = min(RANGE, N_NODES - node0);

    __shared__ int   cnt[RANGE];
    __shared__ float deg[RANGE];
    __shared__ int   sm[RANGE];
    __shared__ int   cur[RANGE];

    cnt[tid] = 0;
    deg[tid] = 0.0f;
    __syncthreads();
    for (int i = tid; i < nE; i += 256) {
        int2 t = ep_tmp[base + i];
        int dl = (t.x >> 17) & (RANGE - 1);
        atomicAdd(&cnt[dl], 1);
        atomicAdd(&deg[dl], __int_as_float(t.y));
    }
    __syncthreads();
    int c = cnt[tid];
    sm[tid] = c;
    __syncthreads();
#pragma unroll
    for (int o = 1; o < 256; o <<= 1) {
        int u = (tid >= o) ? sm[tid - o] : 0;
        __syncthreads();
        sm[tid] += u;
        __syncthreads();
    }
    int excl = sm[tid] - c;
    cur[tid] = base + excl;
    if (tid < nNodes) {
        rp[node0 + tid]  = base + excl;
        dis[node0 + tid] = rsqrtf(deg[tid] + 1.0f);
    }
    if (b == NBUK - 1 && tid == 0) rp[N_NODES] = N_EDGES;
    __syncthreads();
    for (int i = tid; i < nE; i += 256) {
        int2 t = ep_tmp[base + i];
        int dl = (t.x >> 17) & (RANGE - 1);
        int pos = atomicAdd(&cur[dl], 1);
        ep[pos] = make_int2(t.x & 0x1FFFF, t.y);       // (src, ew)
    }
}

// --- fp32 -> bf16 conversion (8 elems/thread, coalesced) -------------------------
__global__ __launch_bounds__(256) void k_cvt(const float4* __restrict__ in,
                                             uint4* __restrict__ out,
                                             int n8)
{
    int i = blockIdx.x * blockDim.x + threadIdx.x;
    if (i >= n8) return;
    float4 a = in[2 * i];
    float4 b = in[2 * i + 1];
    uint4 o;
    o.x = (unsigned)f2b(a.x) | ((unsigned)f2b(a.y) << 16);
    o.y = (unsigned)f2b(a.z) | ((unsigned)f2b(a.w) << 16);
    o.z = (unsigned)f2b(b.x) | ((unsigned)f2b(b.y) << 16);
    o.w = (unsigned)f2b(b.z) | ((unsigned)f2b(b.w) << 16);
    out[i] = o;
}

// --- prepack W into B-fragment layout (lane l: col=l&15, k-octet=l>>4) -----------
template <int KIN, int KOUT>
__global__ __launch_bounds__(256) void k_prepack(const float* __restrict__ W,
                                                 unsigned short* __restrict__ wp)
{
    constexpr int KS = KIN / 32;
    constexpr int NSLOT = (KOUT / 16) * KS * 64;
    int idx = blockIdx.x * blockDim.x + threadIdx.x;
    if (idx >= NSLOT) return;
    int l  = idx & 63;
    int t  = idx >> 6;
    int ks = t % KS;
    int nt = t / KS;
    int col = nt * 16 + (l & 15);
    int k0  = ks * 32 + (l >> 4) * 8;
    unsigned short o[8];
#pragma unroll
    for (int j = 0; j < 8; ++j)
        o[j] = f2b(W[(k0 + j) * KOUT + col]);
    *reinterpret_cast<uint4*>(&wp[(size_t)idx * 8]) = *reinterpret_cast<uint4*>(o);
}

// --- MFMA GEMM with dis-scaled epilogue: C[n] = dis[n] * (A@W) (bf16) ------------
template <int KIN, int KOUT>
__global__ __launch_bounds__(256) void k_gemm_mfma(const unsigned short* __restrict__ Ab,
                                                   const unsigned short* __restrict__ Wp,
                                                   const float* __restrict__ dis,
                                                   unsigned short* __restrict__ C)
{
    constexpr int NT = KOUT / 16;
    constexpr int KS = KIN / 32;
    const int tid  = threadIdx.x;
    const int lane = tid & 63;
    const int wave = blockIdx.x * (blockDim.x >> 6) + (tid >> 6);
    const int row0 = wave * 16;
    if (row0 >= N_NODES) return;

    f32x4 acc[NT];
#pragma unroll
    for (int nt = 0; nt < NT; ++nt)
        acc[nt] = f32x4{0.f, 0.f, 0.f, 0.f};

    const int arow = row0 + (lane & 15);
    const int koff = (lane >> 4) * 8;
#pragma unroll
    for (int ks = 0; ks < KS; ++ks) {
        bf16x8 a = *reinterpret_cast<const bf16x8*>(Ab + (size_t)arow * KIN + ks * 32 + koff);
#pragma unroll
        for (int nt = 0; nt < NT; ++nt) {
            bf16x8 b = *reinterpret_cast<const bf16x8*>(Wp + ((size_t)(nt * KS + ks) * 64 + lane) * 8);
            acc[nt] = __builtin_amdgcn_mfma_f32_16x16x32_bf16(a, b, acc[nt], 0, 0, 0);
        }
    }

    // C/D layout (m89-verified): col = lane&15, row = (lane>>4)*4 + r
    const int r0 = row0 + ((lane >> 4) << 2);
    const int c0 = lane & 15;
    float dv[4];
#pragma unroll
    for (int r = 0; r < 4; ++r) dv[r] = dis[r0 + r];
#pragma unroll
    for (int nt = 0; nt < NT; ++nt) {
#pragma unroll
        for (int r = 0; r < 4; ++r)
            C[(size_t)(r0 + r) * KOUT + nt * 16 + c0] = f2b(acc[nt][r] * dv[r]);
    }
}

// --- CSR gather on dis-premultiplied bf16 rows, 16B loads, fused finalize --------
// out[n] = dis[n] * (sum_e ew_e * xws[src_e] + xws[n]) + b   (+relu / bf16 opt)
template <int DIM, bool RELU, bool OBF16>
__global__ __launch_bounds__(256) void k_gather(const int*  __restrict__ rp,
                                                const int2* __restrict__ ep,
                                                const unsigned short* __restrict__ xws,
                                                const float* __restrict__ dis,
                                                const float* __restrict__ bias,
                                                void* __restrict__ out)
{
    constexpr int TPN = DIM / 8;          // threads per node (16 or 8)
    constexpr int NPB = 256 / TPN;        // nodes per block; N_NODES % NPB == 0
    const int tid = threadIdx.x;
    const int n   = blockIdx.x * NPB + tid / TPN;
    const int d8  = tid % TPN;
    const uint4* xw8 = reinterpret_cast<const uint4*>(xws);
    const int beg = rp[n];
    const int end = rp[n + 1];

    float a0[8] = {0,0,0,0,0,0,0,0};
    float a1[8] = {0,0,0,0,0,0,0,0};

    auto fma8 = [](float w, uint4 u, float* acc) {
        acc[0] = fmaf(w, __uint_as_float(u.x << 16),          acc[0]);
        acc[1] = fmaf(w, __uint_as_float(u.x & 0xFFFF0000u),  acc[1]);
        acc[2] = fmaf(w, __uint_as_float(u.y << 16),          acc[2]);
        acc[3] = fmaf(w, __uint_as_float(u.y & 0xFFFF0000u),  acc[3]);
        acc[4] = fmaf(w, __uint_as_float(u.z << 16),          acc[4]);
        acc[5] = fmaf(w, __uint_as_float(u.z & 0xFFFF0000u),  acc[5]);
        acc[6] = fmaf(w, __uint_as_float(u.w << 16),          acc[6]);
        acc[7] = fmaf(w, __uint_as_float(u.w & 0xFFFF0000u),  acc[7]);
    };

    int i = beg;
    for (; i + 8 <= end; i += 8) {
        int2 e0 = ep[i],     e1 = ep[i + 1], e2 = ep[i + 2], e3 = ep[i + 3];
        int2 e4 = ep[i + 4], e5 = ep[i + 5], e6 = ep[i + 6], e7 = ep[i + 7];
        uint4 u0 = xw8[(size_t)e0.x * TPN + d8];
        uint4 u1 = xw8[(size_t)e1.x * TPN + d8];
        uint4 u2 = xw8[(size_t)e2.x * TPN + d8];
        uint4 u3 = xw8[(size_t)e3.x * TPN + d8];
        uint4 u4 = xw8[(size_t)e4.x * TPN + d8];
        uint4 u5 = xw8[(size_t)e5.x * TPN + d8];
        uint4 u6 = xw8[(size_t)e6.x * TPN + d8];
        uint4 u7 = xw8[(size_t)e7.x * TPN + d8];
        fma8(__int_as_float(e0.y), u0, a0);
        fma8(__int_as_float(e1.y), u1, a1);
        fma8(__int_as_float(e2.y), u2, a0);
        fma8(__int_as_float(e3.y), u3, a1);
        fma8(__int_as_float(e4.y), u4, a0);
        fma8(__int_as_float(e5.y), u5, a1);
        fma8(__int_as_float(e6.y), u6, a0);
        fma8(__int_as_float(e7.y), u7, a1);
    }
    for (; i < end; ++i) {
        int2 e = ep[i];
        uint4 u = xw8[(size_t)e.x * TPN + d8];
        fma8(__int_as_float(e.y), u, a0);
    }
    // self term: + 1.0 * xws[n]
    {
        uint4 un = xw8[(size_t)n * TPN + d8];
        fma8(1.0f, un, a0);
    }

    const float dn = dis[n];
    const float4* b4 = reinterpret_cast<const float4*>(bias);
    float4 blo = b4[d8 * 2];
    float4 bhi = b4[d8 * 2 + 1];
    float v[8];
    v[0] = fmaf(dn, a0[0] + a1[0], blo.x);
    v[1] = fmaf(dn, a0[1] + a1[1], blo.y);
    v[2] = fmaf(dn, a0[2] + a1[2], blo.z);
    v[3] = fmaf(dn, a0[3] + a1[3], blo.w);
    v[4] = fmaf(dn, a0[4] + a1[4], bhi.x);
    v[5] = fmaf(dn, a0[5] + a1[5], bhi.y);
    v[6] = fmaf(dn, a0[6] + a1[6], bhi.z);
    v[7] = fmaf(dn, a0[7] + a1[7], bhi.w);
    if (RELU) {
#pragma unroll
        for (int j = 0; j < 8; ++j) v[j] = fmaxf(v[j], 0.0f);
    }
    if (OBF16) {
        uint4 o;
        o.x = (unsigned)f2b(v[0]) | ((unsigned)f2b(v[1]) << 16);
        o.y = (unsigned)f2b(v[2]) | ((unsigned)f2b(v[3]) << 16);
        o.z = (unsigned)f2b(v[4]) | ((unsigned)f2b(v[5]) << 16);
        o.w = (unsigned)f2b(v[6]) | ((unsigned)f2b(v[7]) << 16);
        reinterpret_cast<uint4*>(out)[(size_t)n * TPN + d8] = o;
    } else {
        float4* o4 = reinterpret_cast<float4*>(out);
        o4[(size_t)n * (DIM / 4) + d8 * 2]     = make_float4(v[0], v[1], v[2], v[3]);
        o4[(size_t)n * (DIM / 4) + d8 * 2 + 1] = make_float4(v[4], v[5], v[6], v[7]);
    }
}

extern "C" void kernel_launch(void* const* d_in, const int* in_sizes, int n_in,
                              void* d_out, int out_size, void* d_ws, size_t ws_size,
                              hipStream_t stream)
{
    const float* x    = (const float*)d_in[0];
    const int*   eidx = (const int*)  d_in[1];   // [2, N_EDGES] int32
    const float* curv = (const float*)d_in[2];   // [N_EDGES, 1]
    const float* W1   = (const float*)d_in[3];
    const float* b1   = (const float*)d_in[4];
    const float* W2   = (const float*)d_in[5];
    const float* b2   = (const float*)d_in[6];
    const float* mw1  = (const float*)d_in[7];
    const float* mb1  = (const float*)d_in[8];
    const float* mw2  = (const float*)d_in[9];
    const float* mb2  = (const float*)d_in[10];

    const int* src = eidx;
    const int* dst = eidx + N_EDGES;
    float* out = (float*)d_out;

    // --- workspace carve-out (~105 MB) ---
    char*  ws  = (char*)d_ws;
    size_t off = 0;
    auto alloc = [&](size_t bytes) -> void* {
        void* p = ws + off;
        off += (bytes + 255) & ~(size_t)255;
        return p;
    };
    float* dis       = (float*)alloc(sizeof(float) * N_NODES);
    int*   rp        = (int*)  alloc(sizeof(int) * (N_NODES + 1));
    int*   gcnt      = (int*)  alloc(sizeof(int) * NBUK);                  // [zeroed]
    int*   bucketBase= (int*)  alloc(sizeof(int) * (NBUK + 1));
    int*   blockHist = (int*)  alloc(sizeof(int) * (size_t)NPART * NBUK);
    int2*  ep_tmp    = (int2*) alloc(sizeof(int2) * N_EDGES);
    int2*  ep        = (int2*) alloc(sizeof(int2) * N_EDGES);              // (src, ew)
    unsigned short* xb  = (unsigned short*)alloc(sizeof(unsigned short) * (size_t)N_NODES * IN_DIM);
    unsigned short* xws = (unsigned short*)alloc(sizeof(unsigned short) * (size_t)N_NODES * HID_DIM);
    unsigned short* h1b = (unsigned short*)alloc(sizeof(unsigned short) * (size_t)N_NODES * HID_DIM);
    unsigned short* wp1 = (unsigned short*)alloc(sizeof(unsigned short) * (HID_DIM / 16) * (IN_DIM / 32) * 64 * 8);
    unsigned short* wp2 = (unsigned short*)alloc(sizeof(unsigned short) * (OUT_DIM / 16) * (HID_DIM / 32) * 64 * 8);

    hipMemsetAsync(gcnt, 0, sizeof(int) * NBUK, stream);

    const int B = 256;
    auto cdiv = [](long long a, long long b) { return (int)((a + b - 1) / b); };

    // CSR build via bucketed counting sort (+deg/dis fused into bucket sort)
    k_hist        <<<NPART, 512, 0, stream>>>(dst, blockHist, gcnt);
    k_scan_buckets<<<1, 512, 0, stream>>>(gcnt, bucketBase);
    k_colscan     <<<cdiv(NBUK, B), B, 0, stream>>>(blockHist, bucketBase);
    k_partition   <<<NPART, 512, 0, stream>>>(curv, src, dst, mw1, mb1, mw2, mb2,
                                              blockHist, ep_tmp);
    k_bucket_sort <<<NBUK, 256, 0, stream>>>(ep_tmp, bucketBase, ep, rp, dis);

    // bf16 input conversion + weight prepack
    k_cvt<<<cdiv((size_t)N_NODES * IN_DIM / 8, B), B, 0, stream>>>(
        (const float4*)x, (uint4*)xb, (int)((size_t)N_NODES * IN_DIM / 8));
    k_prepack<IN_DIM, HID_DIM><<<cdiv((HID_DIM/16)*(IN_DIM/32)*64, B), B, 0, stream>>>(W1, wp1);
    k_prepack<HID_DIM, OUT_DIM><<<cdiv((OUT_DIM/16)*(HID_DIM/32)*64, B), B, 0, stream>>>(W2, wp2);

    const int GEMM_GRID = cdiv(N_NODES / 16, 4);   // 4 waves/block, 16 rows/wave

    // layer 1: xws1 = dis .* (x@W1)  (MFMA, bf16); h1 = relu(dis*(gather+self)+b1)
    k_gemm_mfma<IN_DIM, HID_DIM><<<GEMM_GRID, 256, 0, stream>>>(xb, wp1, dis, xws);
    k_gather<HID_DIM, true, true><<<N_NODES / 16, 256, 0, stream>>>(rp, ep, xws, dis, b1, h1b);

    // layer 2: xws2 = dis .* (h1@W2); out = dis*(gather+self) + b2  (fp32)
    k_gemm_mfma<HID_DIM, OUT_DIM><<<GEMM_GRID, 256, 0, stream>>>(h1b, wp2, dis, xws);
    k_gather<OUT_DIM, false, false><<<N_NODES / 32, 256, 0, stream>>>(rp, ep, xws, dis, b2, out);
}

// Round 12
// 209.827 us; speedup vs baseline: 2.7419x; 1.0871x over previous
//
#include <hip/hip_runtime.h>

// ---------------------------------------------------------------------------
// LearnableCurvGCN, round 11: kill hidden serial colscan, fold cvt into GEMM,
// LDS-stage the bucket sort.
//
// R11 counters: gather<128> 71us @ ~6.1 TB/s logical (byte floor), gather<64>
// ~38us — at roofline. Non-gather plumbing ~120us. Changes:
//   - blockHist transposed to bucket-major [j][b]; colscan = per-bucket block
//     LDS scan (391 blocks) instead of 391 threads x NPART-deep dependent
//     global chains (was a hidden ~30-60us latency serial).
//   - EPB 4096 -> 8192 (NPART=196): partition write runs 2x longer.
//   - k_cvt eliminated: gemm1 loads fp32 x and converts to bf16 in-register.
//   - k_bucket_sort stages the bucket's edges in LDS (48KB, fallback global).
//
// Pipeline:
//   k_hist -> k_scan_buckets -> k_colscan -> k_partition -> k_bucket_sort
//   gemm1(fp32 x) -> gather1(bf16, relu, bf16 out) -> gemm2 -> gather2(fp32 out)
// ---------------------------------------------------------------------------

constexpr int N_NODES = 100000;
constexpr int N_EDGES = 1600000;
constexpr int IN_DIM  = 128;
constexpr int HID_DIM = 128;
constexpr int OUT_DIM = 64;

constexpr int RANGE = 256;                            // nodes per bucket
constexpr int NBUK  = (N_NODES + RANGE - 1) / RANGE;  // 391
constexpr int EPB   = 8192;                           // edges per partition block
constexpr int NPART = (N_EDGES + EPB - 1) / EPB;      // 196
constexpr int STAGE_CAP = 6144;                       // bucket edges LDS cap (48KB)

using bf16x8 = __attribute__((ext_vector_type(8))) short;
using f32x4  = __attribute__((ext_vector_type(4))) float;

// --- helpers -----------------------------------------------------------------
__device__ __forceinline__ unsigned short f2b(float f)
{
    unsigned int u = __float_as_uint(f);
    u += 0x7fffu + ((u >> 16) & 1u);     // round-to-nearest-even
    return (unsigned short)(u >> 16);
}

__device__ __forceinline__ float edge_weight_mlp(float c,
                                                 const float* __restrict__ mw1,
                                                 const float* __restrict__ mb1,
                                                 const float* __restrict__ mw2,
                                                 const float* __restrict__ mb2)
{
    float z = mb2[0];
#pragma unroll
    for (int i = 0; i < 16; ++i) {
        float h = fmaf(c, mw1[i], mb1[i]);
        h = fmaxf(h, 0.0f);
        z = fmaf(h, mw2[i], z);
    }
    float s = 1.0f / (1.0f + __expf(-z));
    return fmaf(0.9f, s, 0.1f);
}

// --- 1. coarse histogram: blockHist[bucket][block] (bucket-major!), gcnt ------
__global__ __launch_bounds__(512) void k_hist(const int* __restrict__ dst,
                                              int* __restrict__ blockHist,
                                              int* __restrict__ gcnt)
{
    __shared__ int hist[NBUK];
    const int tid = threadIdx.x;
    const int b   = blockIdx.x;
    for (int i = tid; i < NBUK; i += 512) hist[i] = 0;
    __syncthreads();
    const int base = b * EPB;
    const int n = min(EPB, N_EDGES - base);
    for (int i = tid; i < n; i += 512)
        atomicAdd(&hist[dst[base + i] >> 8], 1);
    __syncthreads();
    for (int i = tid; i < NBUK; i += 512) {
        int h = hist[i];
        blockHist[(size_t)i * NPART + b] = h;
        if (h) atomicAdd(&gcnt[i], h);
    }
}

// --- 2. bucketBase = exclusive_scan(gcnt); bucketBase[NBUK] = total -----------
__global__ __launch_bounds__(512) void k_scan_buckets(const int* __restrict__ gcnt,
                                                      int* __restrict__ bucketBase)
{
    __shared__ int sm[512];
    const int t = threadIdx.x;
    int v = (t < NBUK) ? gcnt[t] : 0;
    sm[t] = v;
    __syncthreads();
#pragma unroll
    for (int o = 1; o < 512; o <<= 1) {
        int u = (t >= o) ? sm[t - o] : 0;
        __syncthreads();
        sm[t] += u;
        __syncthreads();
    }
    if (t < NBUK) bucketBase[t] = sm[t] - v;
    if (t == NBUK - 1) bucketBase[NBUK] = sm[t];
}

// --- 3. per-bucket scan of its NPART block counts (parallel, LDS) -------------
__global__ __launch_bounds__(256) void k_colscan(int* __restrict__ blockHist,
                                                 const int* __restrict__ bucketBase)
{
    const int j = blockIdx.x;
    const int t = threadIdx.x;
    __shared__ int sm[256];
    int v = (t < NPART) ? blockHist[(size_t)j * NPART + t] : 0;
    sm[t] = v;
    __syncthreads();
#pragma unroll
    for (int o = 1; o < 256; o <<= 1) {
        int u = (t >= o) ? sm[t - o] : 0;
        __syncthreads();
        sm[t] += u;
        __syncthreads();
    }
    if (t < NPART)
        blockHist[(size_t)j * NPART + t] = bucketBase[j] + sm[t] - v;
}

// --- 4. partition edges into coarse-bucket segments ----------------------------
__global__ __launch_bounds__(512) void k_partition(const float* __restrict__ curv,
                                                   const int*   __restrict__ src,
                                                   const int*   __restrict__ dst,
                                                   const float* __restrict__ mw1,
                                                   const float* __restrict__ mb1,
                                                   const float* __restrict__ mw2,
                                                   const float* __restrict__ mb2,
                                                   const int*   __restrict__ blockHist,
                                                   int2* __restrict__ ep_tmp)
{
    __shared__ int cur[NBUK];
    const int tid = threadIdx.x;
    const int b   = blockIdx.x;
    for (int i = tid; i < NBUK; i += 512)
        cur[i] = blockHist[(size_t)i * NPART + b];
    __syncthreads();
    const int base = b * EPB;
    const int n = min(EPB, N_EDGES - base);
    for (int i = tid; i < n; i += 512) {
        int e = base + i;
        int d = dst[e];
        float w = edge_weight_mlp(curv[e], mw1, mb1, mw2, mb2);
        int pos = atomicAdd(&cur[d >> 8], 1);
        int meta = src[e] | ((d & (RANGE - 1)) << 17);   // src<2^17, dl<256
        ep_tmp[pos] = make_int2(meta, __float_as_int(w));
    }
}

// --- 5. per-bucket counting sort + deg + dis + rp (LDS-staged) -----------------
__global__ __launch_bounds__(256) void k_bucket_sort(const int2* __restrict__ ep_tmp,
                                                     const int*  __restrict__ bucketBase,
                                                     int2* __restrict__ ep,
                                                     int*  __restrict__ rp,
                                                     float* __restrict__ dis)
{
    const int b   = blockIdx.x;
    const int tid = threadIdx.x;
    const int base  = bucketBase[b];
    const int nE    = bucketBase[b + 1] - base;
    const int node0 = b * RANGE;
    const int nNodes = min(RANGE, N_NODES - node0);

    __shared__ int2  stage[STAGE_CAP];     // 48KB
    __shared__ int   cnt[RANGE];
    __shared__ float deg[RANGE];
    __shared__ int   sm[RANGE];
    __shared__ int   cur[RANGE];

    const bool fit = (nE <= STAGE_CAP);

    cnt[tid] = 0;
    deg[tid] = 0.0f;
    __syncthreads();
    for (int i = tid; i < nE; i += 256) {
        int2 t = ep_tmp[base + i];
        if (fit) stage[i] = t;
        int dl = (t.x >> 17) & (RANGE - 1);
        atomicAdd(&cnt[dl], 1);
        atomicAdd(&deg[dl], __int_as_float(t.y));
    }
    __syncthreads();
    int c = cnt[tid];
    sm[tid] = c;
    __syncthreads();
#pragma unroll
    for (int o = 1; o < 256; o <<= 1) {
        int u = (tid >= o) ? sm[tid - o] : 0;
        __syncthreads();
        sm[tid] += u;
        __syncthreads();
    }
    int excl = sm[tid] - c;
    cur[tid] = base + excl;
    if (tid < nNodes) {
        rp[node0 + tid]  = base + excl;
        dis[node0 + tid] = rsqrtf(deg[tid] + 1.0f);
    }
    if (b == NBUK - 1 && tid == 0) rp[N_NODES] = N_EDGES;
    __syncthreads();
    for (int i = tid; i < nE; i += 256) {
        int2 t = fit ? stage[i] : ep_tmp[base + i];
        int dl = (t.x >> 17) & (RANGE - 1);
        int pos = atomicAdd(&cur[dl], 1);
        ep[pos] = make_int2(t.x & 0x1FFFF, t.y);       // (src, ew)
    }
}

// --- prepack W into B-fragment layout (lane l: col=l&15, k-octet=l>>4) -----------
template <int KIN, int KOUT>
__global__ __launch_bounds__(256) void k_prepack(const float* __restrict__ W,
                                                 unsigned short* __restrict__ wp)
{
    constexpr int KS = KIN / 32;
    constexpr int NSLOT = (KOUT / 16) * KS * 64;
    int idx = blockIdx.x * blockDim.x + threadIdx.x;
    if (idx >= NSLOT) return;
    int l  = idx & 63;
    int t  = idx >> 6;
    int ks = t % KS;
    int nt = t / KS;
    int col = nt * 16 + (l & 15);
    int k0  = ks * 32 + (l >> 4) * 8;
    unsigned short o[8];
#pragma unroll
    for (int j = 0; j < 8; ++j)
        o[j] = f2b(W[(k0 + j) * KOUT + col]);
    *reinterpret_cast<uint4*>(&wp[(size_t)idx * 8]) = *reinterpret_cast<uint4*>(o);
}

// --- MFMA GEMM, dis-scaled epilogue; A either fp32 (in-reg cvt) or bf16 ---------
template <int KIN, int KOUT, bool AFP32>
__global__ __launch_bounds__(256) void k_gemm_mfma(const void* __restrict__ Aptr,
                                                   const unsigned short* __restrict__ Wp,
                                                   const float* __restrict__ dis,
                                                   unsigned short* __restrict__ C)
{
    constexpr int NT = KOUT / 16;
    constexpr int KS = KIN / 32;
    const int tid  = threadIdx.x;
    const int lane = tid & 63;
    const int wave = blockIdx.x * (blockDim.x >> 6) + (tid >> 6);
    const int row0 = wave * 16;
    if (row0 >= N_NODES) return;

    f32x4 acc[NT];
#pragma unroll
    for (int nt = 0; nt < NT; ++nt)
        acc[nt] = f32x4{0.f, 0.f, 0.f, 0.f};

    const int arow = row0 + (lane & 15);
    const int koff = (lane >> 4) * 8;
#pragma unroll
    for (int ks = 0; ks < KS; ++ks) {
        bf16x8 a;
        if constexpr (AFP32) {
            const float* A = (const float*)Aptr;
            const float* p = A + (size_t)arow * KIN + ks * 32 + koff;
            float4 f0 = *reinterpret_cast<const float4*>(p);
            float4 f1 = *reinterpret_cast<const float4*>(p + 4);
            a[0] = (short)f2b(f0.x); a[1] = (short)f2b(f0.y);
            a[2] = (short)f2b(f0.z); a[3] = (short)f2b(f0.w);
            a[4] = (short)f2b(f1.x); a[5] = (short)f2b(f1.y);
            a[6] = (short)f2b(f1.z); a[7] = (short)f2b(f1.w);
        } else {
            const unsigned short* A = (const unsigned short*)Aptr;
            a = *reinterpret_cast<const bf16x8*>(A + (size_t)arow * KIN + ks * 32 + koff);
        }
#pragma unroll
        for (int nt = 0; nt < NT; ++nt) {
            bf16x8 bfr = *reinterpret_cast<const bf16x8*>(Wp + ((size_t)(nt * KS + ks) * 64 + lane) * 8);
            acc[nt] = __builtin_amdgcn_mfma_f32_16x16x32_bf16(a, bfr, acc[nt], 0, 0, 0);
        }
    }

    // C/D layout (m89-verified): col = lane&15, row = (lane>>4)*4 + r
    const int r0 = row0 + ((lane >> 4) << 2);
    const int c0 = lane & 15;
    float dv[4];
#pragma unroll
    for (int r = 0; r < 4; ++r) dv[r] = dis[r0 + r];
#pragma unroll
    for (int nt = 0; nt < NT; ++nt) {
#pragma unroll
        for (int r = 0; r < 4; ++r)
            C[(size_t)(r0 + r) * KOUT + nt * 16 + c0] = f2b(acc[nt][r] * dv[r]);
    }
}

// --- CSR gather on dis-premultiplied bf16 rows, 16B loads, fused finalize --------
// out[n] = dis[n] * (sum_e ew_e * xws[src_e] + xws[n]) + b   (+relu / bf16 opt)
template <int DIM, bool RELU, bool OBF16>
__global__ __launch_bounds__(256) void k_gather(const int*  __restrict__ rp,
                                                const int2* __restrict__ ep,
                                                const unsigned short* __restrict__ xws,
                                                const float* __restrict__ dis,
                                                const float* __restrict__ bias,
                                                void* __restrict__ out)
{
    constexpr int TPN = DIM / 8;          // threads per node (16 or 8)
    constexpr int NPB = 256 / TPN;        // nodes per block; N_NODES % NPB == 0
    const int tid = threadIdx.x;
    const int n   = blockIdx.x * NPB + tid / TPN;
    const int d8  = tid % TPN;
    const uint4* xw8 = reinterpret_cast<const uint4*>(xws);
    const int beg = rp[n];
    const int end = rp[n + 1];

    float a0[8] = {0,0,0,0,0,0,0,0};
    float a1[8] = {0,0,0,0,0,0,0,0};

    auto fma8 = [](float w, uint4 u, float* acc) {
        acc[0] = fmaf(w, __uint_as_float(u.x << 16),          acc[0]);
        acc[1] = fmaf(w, __uint_as_float(u.x & 0xFFFF0000u),  acc[1]);
        acc[2] = fmaf(w, __uint_as_float(u.y << 16),          acc[2]);
        acc[3] = fmaf(w, __uint_as_float(u.y & 0xFFFF0000u),  acc[3]);
        acc[4] = fmaf(w, __uint_as_float(u.z << 16),          acc[4]);
        acc[5] = fmaf(w, __uint_as_float(u.z & 0xFFFF0000u),  acc[5]);
        acc[6] = fmaf(w, __uint_as_float(u.w << 16),          acc[6]);
        acc[7] = fmaf(w, __uint_as_float(u.w & 0xFFFF0000u),  acc[7]);
    };

    int i = beg;
    for (; i + 8 <= end; i += 8) {
        int2 e0 = ep[i],     e1 = ep[i + 1], e2 = ep[i + 2], e3 = ep[i + 3];
        int2 e4 = ep[i + 4], e5 = ep[i + 5], e6 = ep[i + 6], e7 = ep[i + 7];
        uint4 u0 = xw8[(size_t)e0.x * TPN + d8];
        uint4 u1 = xw8[(size_t)e1.x * TPN + d8];
        uint4 u2 = xw8[(size_t)e2.x * TPN + d8];
        uint4 u3 = xw8[(size_t)e3.x * TPN + d8];
        uint4 u4 = xw8[(size_t)e4.x * TPN + d8];
        uint4 u5 = xw8[(size_t)e5.x * TPN + d8];
        uint4 u6 = xw8[(size_t)e6.x * TPN + d8];
        uint4 u7 = xw8[(size_t)e7.x * TPN + d8];
        fma8(__int_as_float(e0.y), u0, a0);
        fma8(__int_as_float(e1.y), u1, a1);
        fma8(__int_as_float(e2.y), u2, a0);
        fma8(__int_as_float(e3.y), u3, a1);
        fma8(__int_as_float(e4.y), u4, a0);
        fma8(__int_as_float(e5.y), u5, a1);
        fma8(__int_as_float(e6.y), u6, a0);
        fma8(__int_as_float(e7.y), u7, a1);
    }
    for (; i < end; ++i) {
        int2 e = ep[i];
        uint4 u = xw8[(size_t)e.x * TPN + d8];
        fma8(__int_as_float(e.y), u, a0);
    }
    // self term: + 1.0 * xws[n]
    {
        uint4 un = xw8[(size_t)n * TPN + d8];
        fma8(1.0f, un, a0);
    }

    const float dn = dis[n];
    const float4* b4 = reinterpret_cast<const float4*>(bias);
    float4 blo = b4[d8 * 2];
    float4 bhi = b4[d8 * 2 + 1];
    float v[8];
    v[0] = fmaf(dn, a0[0] + a1[0], blo.x);
    v[1] = fmaf(dn, a0[1] + a1[1], blo.y);
    v[2] = fmaf(dn, a0[2] + a1[2], blo.z);
    v[3] = fmaf(dn, a0[3] + a1[3], blo.w);
    v[4] = fmaf(dn, a0[4] + a1[4], bhi.x);
    v[5] = fmaf(dn, a0[5] + a1[5], bhi.y);
    v[6] = fmaf(dn, a0[6] + a1[6], bhi.z);
    v[7] = fmaf(dn, a0[7] + a1[7], bhi.w);
    if (RELU) {
#pragma unroll
        for (int j = 0; j < 8; ++j) v[j] = fmaxf(v[j], 0.0f);
    }
    if (OBF16) {
        uint4 o;
        o.x = (unsigned)f2b(v[0]) | ((unsigned)f2b(v[1]) << 16);
        o.y = (unsigned)f2b(v[2]) | ((unsigned)f2b(v[3]) << 16);
        o.z = (unsigned)f2b(v[4]) | ((unsigned)f2b(v[5]) << 16);
        o.w = (unsigned)f2b(v[6]) | ((unsigned)f2b(v[7]) << 16);
        reinterpret_cast<uint4*>(out)[(size_t)n * TPN + d8] = o;
    } else {
        float4* o4 = reinterpret_cast<float4*>(out);
        o4[(size_t)n * (DIM / 4) + d8 * 2]     = make_float4(v[0], v[1], v[2], v[3]);
        o4[(size_t)n * (DIM / 4) + d8 * 2 + 1] = make_float4(v[4], v[5], v[6], v[7]);
    }
}

extern "C" void kernel_launch(void* const* d_in, const int* in_sizes, int n_in,
                              void* d_out, int out_size, void* d_ws, size_t ws_size,
                              hipStream_t stream)
{
    const float* x    = (const float*)d_in[0];
    const int*   eidx = (const int*)  d_in[1];   // [2, N_EDGES] int32
    const float* curv = (const float*)d_in[2];   // [N_EDGES, 1]
    const float* W1   = (const float*)d_in[3];
    const float* b1   = (const float*)d_in[4];
    const float* W2   = (const float*)d_in[5];
    const float* b2   = (const float*)d_in[6];
    const float* mw1  = (const float*)d_in[7];
    const float* mb1  = (const float*)d_in[8];
    const float* mw2  = (const float*)d_in[9];
    const float* mb2  = (const float*)d_in[10];

    const int* src = eidx;
    const int* dst = eidx + N_EDGES;
    float* out = (float*)d_out;

    // --- workspace carve-out (~78 MB) ---
    char*  ws  = (char*)d_ws;
    size_t off = 0;
    auto alloc = [&](size_t bytes) -> void* {
        void* p = ws + off;
        off += (bytes + 255) & ~(size_t)255;
        return p;
    };
    float* dis       = (float*)alloc(sizeof(float) * N_NODES);
    int*   rp        = (int*)  alloc(sizeof(int) * (N_NODES + 1));
    int*   gcnt      = (int*)  alloc(sizeof(int) * NBUK);                  // [zeroed]
    int*   bucketBase= (int*)  alloc(sizeof(int) * (NBUK + 1));
    int*   blockHist = (int*)  alloc(sizeof(int) * (size_t)NBUK * NPART);  // bucket-major
    int2*  ep_tmp    = (int2*) alloc(sizeof(int2) * N_EDGES);
    int2*  ep        = (int2*) alloc(sizeof(int2) * N_EDGES);              // (src, ew)
    unsigned short* xws = (unsigned short*)alloc(sizeof(unsigned short) * (size_t)N_NODES * HID_DIM);
    unsigned short* h1b = (unsigned short*)alloc(sizeof(unsigned short) * (size_t)N_NODES * HID_DIM);
    unsigned short* wp1 = (unsigned short*)alloc(sizeof(unsigned short) * (HID_DIM / 16) * (IN_DIM / 32) * 64 * 8);
    unsigned short* wp2 = (unsigned short*)alloc(sizeof(unsigned short) * (OUT_DIM / 16) * (HID_DIM / 32) * 64 * 8);

    hipMemsetAsync(gcnt, 0, sizeof(int) * NBUK, stream);

    const int B = 256;
    auto cdiv = [](long long a, long long b) { return (int)((a + b - 1) / b); };

    // CSR build via bucketed counting sort (deg/dis fused into bucket sort)
    k_hist        <<<NPART, 512, 0, stream>>>(dst, blockHist, gcnt);
    k_scan_buckets<<<1, 512, 0, stream>>>(gcnt, bucketBase);
    k_colscan     <<<NBUK, 256, 0, stream>>>(blockHist, bucketBase);
    k_partition   <<<NPART, 512, 0, stream>>>(curv, src, dst, mw1, mb1, mw2, mb2,
                                              blockHist, ep_tmp);
    k_bucket_sort <<<NBUK, 256, 0, stream>>>(ep_tmp, bucketBase, ep, rp, dis);

    // weight prepack (tiny)
    k_prepack<IN_DIM, HID_DIM><<<cdiv((HID_DIM/16)*(IN_DIM/32)*64, B), B, 0, stream>>>(W1, wp1);
    k_prepack<HID_DIM, OUT_DIM><<<cdiv((OUT_DIM/16)*(HID_DIM/32)*64, B), B, 0, stream>>>(W2, wp2);

    const int GEMM_GRID = cdiv(N_NODES / 16, 4);   // 4 waves/block, 16 rows/wave

    // layer 1: xws1 = dis .* (x@W1)  (MFMA, fp32 A with in-reg cvt)
    k_gemm_mfma<IN_DIM, HID_DIM, true><<<GEMM_GRID, 256, 0, stream>>>(x, wp1, dis, xws);
    k_gather<HID_DIM, true, true><<<N_NODES / 16, 256, 0, stream>>>(rp, ep, xws, dis, b1, h1b);

    // layer 2: xws2 = dis .* (h1@W2); out = dis*(gather+self) + b2  (fp32)
    k_gemm_mfma<HID_DIM, OUT_DIM, false><<<GEMM_GRID, 256, 0, stream>>>(h1b, wp2, dis, xws);
    k_gather<OUT_DIM, false, false><<<N_NODES / 32, 256, 0, stream>>>(rp, ep, xws, dis, b2, out);
}